// Round 13
// baseline (310.372 us; speedup 1.0000x reference)
//
#include <hip/hip_runtime.h>
#include <cstdint>
#include <cstddef>

#define DIM    2048
#define HEADS  16
#define DH     128
#define INNER  2048
#define SEQ    2048
#define BATCH  2
#define NTOK   4096

typedef unsigned short u16;
typedef __attribute__((ext_vector_type(4))) short bf16x4;
typedef __attribute__((ext_vector_type(8))) short bf16x8;
typedef __attribute__((ext_vector_type(4))) float f32x4;

__device__ __forceinline__ u16 f2bf(float f) {
  union { float f; unsigned u; } v; v.f = f;
  unsigned r = v.u + 0x7FFFu + ((v.u >> 16) & 1u);
  return (u16)(r >> 16);
}
__device__ __forceinline__ float bf2f(u16 h) {
  union { unsigned u; float f; } v; v.u = ((unsigned)h) << 16;
  return v.f;
}

using as1_t = __attribute__((address_space(1))) const void;
using as3_t = __attribute__((address_space(3))) void;
__device__ __forceinline__ void gload_lds16(const void* g, void* l) {
  __builtin_amdgcn_global_load_lds((as1_t*)g, (as3_t*)l, 16, 0, 0);
}

__device__ __forceinline__ f32x4 mfma16(bf16x8 a, bf16x8 b, f32x4 c) {
  return __builtin_amdgcn_mfma_f32_16x16x32_bf16(a, b, c, 0, 0, 0);
}

// ---------------- weight transpose + cast, vectorized: W[K][N] -> Wt[N][K] -
__global__ __launch_bounds__(256)
void transpose_cast(const float* __restrict__ W, u16* __restrict__ Wt,
                    int K, int N) {
  __shared__ float t[64][65];
  const int tiles_n = N >> 6;
  const int tx = blockIdx.x % tiles_n, ty = blockIdx.x / tiles_n;
  const int tid = threadIdx.x;
  const int k0 = ty << 6, n0 = tx << 6;
  #pragma unroll
  for (int i = 0; i < 4; ++i) {       // 64 k-rows x 16 float4
    int e = tid + i * 256;
    int kr = e >> 4, c4 = e & 15;
    *(float4*)&t[kr][c4 * 4] =
        *(const float4*)&W[(size_t)(k0 + kr) * N + n0 + c4 * 4];
  }
  __syncthreads();
  #pragma unroll
  for (int i = 0; i < 2; ++i) {       // 64 n-rows x 8 k8-chunks
    int e = tid + i * 256;
    int nr = e >> 3, k8 = e & 7;
    u16 o[8];
    #pragma unroll
    for (int j = 0; j < 8; ++j) o[j] = f2bf(t[k8 * 8 + j][nr]);
    *(uint4*)&Wt[(size_t)(n0 + nr) * K + k0 + k8 * 8] = *(const uint4*)o;
  }
}

// ---------------- rope cos/sin tables (bf16) ----------------
__global__ __launch_bounds__(256)
void build_tables(const float* __restrict__ rot, u16* __restrict__ cosT,
                  u16* __restrict__ sinT) {
  int i = blockIdx.x * 256 + threadIdx.x;
  float v = rot[i];
  cosT[i] = f2bf(cosf(v));
  sinT[i] = f2bf(sinf(v));
}

// ---------------- RMSNorm: x f32 [NTOK][DIM] -> xn bf16 ----------------
__global__ __launch_bounds__(256)
void rmsnorm_k(const float* __restrict__ x, const float* __restrict__ gw,
               u16* __restrict__ xn) {
  const int row = blockIdx.x, tid = threadIdx.x;
  const float4* x4 = (const float4*)(x + (size_t)row * DIM);
  float4 a = x4[tid * 2], b = x4[tid * 2 + 1];
  float ss = a.x*a.x + a.y*a.y + a.z*a.z + a.w*a.w
           + b.x*b.x + b.y*b.y + b.z*b.z + b.w*b.w;
  #pragma unroll
  for (int off = 1; off < 64; off <<= 1) ss += __shfl_xor(ss, off);
  __shared__ float red[4];
  if ((tid & 63) == 0) red[tid >> 6] = ss;
  __syncthreads();
  float tot = red[0] + red[1] + red[2] + red[3];
  float sc = 1.0f / fmaxf(sqrtf(tot * (1.0f / DIM)), 1e-8f);
  const float4* g4 = (const float4*)gw;
  float4 ga = g4[tid * 2], gb = g4[tid * 2 + 1];
  u16 ov[8];
  ov[0] = f2bf(a.x * sc * ga.x); ov[1] = f2bf(a.y * sc * ga.y);
  ov[2] = f2bf(a.z * sc * ga.z); ov[3] = f2bf(a.w * sc * ga.w);
  ov[4] = f2bf(b.x * sc * gb.x); ov[5] = f2bf(b.y * sc * gb.y);
  ov[6] = f2bf(b.z * sc * gb.z); ov[7] = f2bf(b.w * sc * gb.w);
  *(uint4*)(xn + (size_t)row * DIM + tid * 8) = *(const uint4*)ov;
}

// ---------------- fused QKV GEMM: 128x256, 2-slot dbuf, 2 blocks/CU -------
// (R8 config, banked best: ~130us / MfmaUtil 34.5 / 0 conflicts. PARKED.)
__global__ __launch_bounds__(512, 4)
void gemm_qkv(const u16* __restrict__ A, const u16* __restrict__ Bt,
              u16* __restrict__ C, int M, int N, int K) {
  __shared__ __align__(16) u16 lA[2][128 * 32];
  __shared__ __align__(16) u16 lB[2][256 * 32];
  const int tid = threadIdx.x;
  const int wave = tid >> 6, lane = tid & 63;
  const int r = lane & 15, g = lane >> 4;
  const int wr = wave >> 2, wc = wave & 3;   // 2M x 4N wave grid

  const int bid = blockIdx.x;
  const int wg = (bid & 7) * 96 + (bid >> 3);   // XCD-chunked, 768%8==0
  const int mtile = wg & 31;                    // inner: A panel streams
  const int ntile = wg >> 5;                    // 0..23: B panel L2-resident

  const u16* Abase = A + (size_t)mtile * 128 * K;
  const u16* Bbase = Bt + (size_t)ntile * 256 * K;
  const int nk = K >> 5;   // 64 K-tiles

  auto stA = [&](int j) {            // 8 KB: 1 issue/thread
    int kk = j << 5;
    int row = tid >> 2;
    int col = ((tid & 3) ^ ((row >> 1) & 3)) << 3;
    gload_lds16(Abase + (size_t)row * K + kk + col, &lA[j & 1][wave * 512]);
  };
  auto stB = [&](int j) {            // 16 KB: 2 issues/thread
    int kk = j << 5;
    #pragma unroll
    for (int c = 0; c < 2; ++c) {
      int chunk = c * 512 + tid;
      int row = chunk >> 2;
      int col = ((chunk & 3) ^ ((row >> 1) & 3)) << 3;
      gload_lds16(Bbase + (size_t)row * K + kk + col,
                  &lB[j & 1][c * 4096 + wave * 512]);
    }
  };

  f32x4 acc[4][4];
  const f32x4 z4 = {0.f, 0.f, 0.f, 0.f};
  #pragma unroll
  for (int i = 0; i < 4; ++i)
    #pragma unroll
    for (int j = 0; j < 4; ++j) acc[i][j] = z4;

  const int sw8 = ((g ^ ((r >> 1) & 3)) << 3);
  const int laneA = (wr * 64 + r) * 32 + sw8;
  const int laneB = (wc * 64 + r) * 32 + sw8;

  stA(0); stB(0);
  asm volatile("s_waitcnt vmcnt(0)" ::: "memory");
  __builtin_amdgcn_s_barrier();

  for (int j = 0; j < nk; ++j) {
    if (j + 1 < nk) { stA(j + 1); stB(j + 1); }   // writes slot (j+1)&1
    const u16* bA = &lA[j & 1][0];
    const u16* bB = &lB[j & 1][0];
    bf16x8 af[4], bf[4];
    #pragma unroll
    for (int mi = 0; mi < 4; ++mi)
      af[mi] = *(const bf16x8*)&bA[laneA + mi * 512];
    #pragma unroll
    for (int ni = 0; ni < 4; ++ni)
      bf[ni] = *(const bf16x8*)&bB[laneB + ni * 512];
    __builtin_amdgcn_s_setprio(1);
    #pragma unroll
    for (int mi = 0; mi < 4; ++mi)
      #pragma unroll
      for (int ni = 0; ni < 4; ++ni)
        acc[mi][ni] = mfma16(af[mi], bf[ni], acc[mi][ni]);
    __builtin_amdgcn_s_setprio(0);
    asm volatile("s_waitcnt vmcnt(0)" ::: "memory");  // drain prefetch j+1
    __builtin_amdgcn_s_barrier();                     // all reads of slot done
  }

  #pragma unroll
  for (int mi = 0; mi < 4; ++mi)
    #pragma unroll
    for (int ni = 0; ni < 4; ++ni)
      #pragma unroll
      for (int rr = 0; rr < 4; ++rr) {
        int row = mtile * 128 + wr * 64 + mi * 16 + g * 4 + rr;
        int col = ntile * 256 + wc * 64 + ni * 16 + r;
        C[(size_t)row * N + col] = f2bf(acc[mi][ni][rr]);
      }
}

// ---------------- GEMM 128x128 (O-projection), XCD-chunked flat grid ------
template<int F32OUT>
__global__ __launch_bounds__(256, 3)
void gemm128(const u16* __restrict__ A, const u16* __restrict__ Bt,
             void* __restrict__ C, int M, int N, int K) {
  const int tid = threadIdx.x;
  const int wave = tid >> 6, lane = tid & 63;
  const int bid = blockIdx.x;
  const int wg = (bid & 7) * (gridDim.x >> 3) + (bid >> 3);  // XCD-chunked
  const int mt = wg & 31, nt0 = wg >> 5;
  __shared__ __align__(16) u16 ldsA[2][128 * 32];
  __shared__ __align__(16) u16 ldsB[2][128 * 32];

  const int wm = (wave >> 1) * 64, wn = (wave & 1) * 64;
  const int r = lane & 15, g = lane >> 4;

  f32x4 acc[4][4];
  const f32x4 z4 = {0.f, 0.f, 0.f, 0.f};
  #pragma unroll
  for (int i = 0; i < 4; ++i)
    #pragma unroll
    for (int j = 0; j < 4; ++j) acc[i][j] = z4;

  const u16* Abase = A + (size_t)mt * 128 * K;
  const u16* Bbase = Bt + (size_t)nt0 * 128 * K;

  auto stage = [&](u16* dst, const u16* src, int kb) {
    #pragma unroll
    for (int c = 0; c < 2; ++c) {
      int chunk = wave * 128 + c * 64 + lane;
      int row = chunk >> 2;
      int colb = (chunk & 3) << 4;
      int scolb = colb ^ (((row >> 1) & 3) << 4);
      gload_lds16(src + (size_t)row * K + kb + (scolb >> 1),
                  dst + (wave * 128 + c * 64) * 8);
    }
  };

  const int nk = K >> 5;
  stage(ldsA[0], Abase, 0);
  stage(ldsB[0], Bbase, 0);
  __syncthreads();

  for (int kt = 0; kt < nk; ++kt) {
    const int cur = kt & 1;
    if (kt + 1 < nk) {
      stage(ldsA[cur ^ 1], Abase, (kt + 1) << 5);
      stage(ldsB[cur ^ 1], Bbase, (kt + 1) << 5);
    }
    bf16x8 af[4], bfr[4];
    #pragma unroll
    for (int mi = 0; mi < 4; ++mi) {
      int row = wm + mi * 16 + r;
      int off = row * 32 + (((g << 4) ^ (((row >> 1) & 3) << 4)) >> 1);
      af[mi] = *(const bf16x8*)&ldsA[cur][off];
    }
    #pragma unroll
    for (int ni = 0; ni < 4; ++ni) {
      int row = wn + ni * 16 + r;
      int off = row * 32 + (((g << 4) ^ (((row >> 1) & 3) << 4)) >> 1);
      bfr[ni] = *(const bf16x8*)&ldsB[cur][off];
    }
    __builtin_amdgcn_s_setprio(1);
    #pragma unroll
    for (int mi = 0; mi < 4; ++mi)
      #pragma unroll
      for (int ni = 0; ni < 4; ++ni)
        acc[mi][ni] = mfma16(af[mi], bfr[ni], acc[mi][ni]);
    __builtin_amdgcn_s_setprio(0);
    __syncthreads();
  }

  #pragma unroll
  for (int mi = 0; mi < 4; ++mi)
    #pragma unroll
    for (int ni = 0; ni < 4; ++ni)
      #pragma unroll
      for (int rr = 0; rr < 4; ++rr) {
        int row = mt * 128 + wm + mi * 16 + g * 4 + rr;
        int col = nt0 * 128 + wn + ni * 16 + r;
        float v = acc[mi][ni][rr];
        if (F32OUT) ((float*)C)[(size_t)row * N + col] = v;
        else        ((u16*)C)[(size_t)row * N + col] = f2bf(v);
      }
}

// ---------------- RoPE + rearrange (vectorized 8/thread) ------------------
__global__ __launch_bounds__(256)
void rope_rearrange(const u16* __restrict__ src, int ldsrc,
                    const u16* __restrict__ cosT, const u16* __restrict__ sinT,
                    u16* __restrict__ dst, float scale) {
  int id = blockIdx.x * 256 + threadIdx.x;
  int c8 = id & 7;               // 8-elem chunk within [0,64)
  int hh = (id >> 3) & 15;
  int tok = id >> 7;             // 0..32767
  int n = tok & (SEQ - 1);
  int b = tok >> 11;
  const u16* s = src + (size_t)tok * ldsrc + hh * DH + c8 * 8;
  uint4 d1 = *(const uint4*)s;
  uint4 d2 = *(const uint4*)(s + 64);
  const u16* ct = cosT + n * DH + c8 * 8;
  const u16* st = sinT + n * DH + c8 * 8;
  uint4 c1 = *(const uint4*)ct, c2 = *(const uint4*)(ct + 64);
  uint4 s1 = *(const uint4*)st, s2 = *(const uint4*)(st + 64);
  const u16* d1p = (const u16*)&d1; const u16* d2p = (const u16*)&d2;
  const u16* c1p = (const u16*)&c1; const u16* c2p = (const u16*)&c2;
  const u16* s1p = (const u16*)&s1; const u16* s2p = (const u16*)&s2;
  u16 o1[8], o2[8];
  #pragma unroll
  for (int i = 0; i < 8; ++i) {
    float t1 = bf2f(d1p[i]), t2 = bf2f(d2p[i]);
    o1[i] = f2bf((t1 * bf2f(c1p[i]) - t2 * bf2f(s1p[i])) * scale);
    o2[i] = f2bf((t2 * bf2f(c2p[i]) + t1 * bf2f(s2p[i])) * scale);
  }
  u16* dp = dst + ((size_t)(b * HEADS + hh) * SEQ + n) * DH + c8 * 8;
  *(uint4*)dp = *(const uint4*)o1;
  *(uint4*)(dp + 64) = *(const uint4*)o2;
}

// ---------------- V transpose: v0[NTOK][ld] -> vT[B][H][DH][SEQ] ----------
__global__ __launch_bounds__(256)
void transp_v(const u16* __restrict__ v0, int ld, u16* __restrict__ vTo) {
  __shared__ __align__(16) u16 t[32][136];
  const int id = blockIdx.x;
  const int ntile = id & 63;
  const int hh = (id >> 6) & 15;
  const int b = id >> 10;
  const int tid = threadIdx.x;
  const int n0 = ntile * 32;
  #pragma unroll
  for (int it = 0; it < 2; ++it) {
    int chunk = it * 256 + tid;
    int nr = chunk >> 4, dc = chunk & 15;
    const u16* src = v0 + (size_t)(b * SEQ + n0 + nr) * ld + hh * DH + dc * 8;
    *(uint4*)&t[nr][dc * 8] = *(const uint4*)src;
  }
  __syncthreads();
  int d = tid >> 1, nh = tid & 1;
  u16 tmp[16];
  #pragma unroll
  for (int j = 0; j < 16; ++j) tmp[j] = t[nh * 16 + j][d];
  u16* dst = vTo + ((size_t)(b * HEADS + hh) * DH + d) * SEQ + n0 + nh * 16;
  *(uint4*)&dst[0] = *(const uint4*)&tmp[0];
  *(uint4*)&dst[8] = *(const uint4*)&tmp[8];
}

// ---------------- flash attention (causal), 32 q-rows/wave ----------------
// LDS-read-bound fix: kf/vf tile reads (32 b128/wave/iter) now feed 64 MFMA
// instead of 32 -> reads/MFMA 1.06 -> 0.56. Geometry: 8-wave blocks, wave w
// of block j owns q-group G = w*8+j (32 rows); 64 groups/head x 32 heads =
// 2048 groups = 256 blocks x 8 waves = chip wave capacity at 2 waves/SIMD
// (launch_bounds(512,2) -> 256-VGPR cap; ~220 used). Strided G makes
// per-block total MFMA uniform (balance without pairing); inactive kv-iters
// guarded per wave (wave-uniform branch; barriers outside). Swapped-QK^T
// in-register softmax with TWO q-col frags (m/lsum/alpha per qc). T1 XCD
// swizzle: 4 heads' K/V per XCD L2. LDS 96 KB (kT+vS 2-slot + 8x4KB pS).
__global__ __launch_bounds__(512, 2)
void flash(const u16* __restrict__ qr, const u16* __restrict__ kr,
           const u16* __restrict__ vT, u16* __restrict__ attn) {
  const int bid = blockIdx.x;
  const int swz = (bid & 7) * 32 + (bid >> 3);   // T1 remap, 256%8==0
  const int hb = swz >> 3, j = swz & 7;          // 4 heads per XCD
  const int h = hb & 15, b = hb >> 4;
  const int tid = threadIdx.x, wave = tid >> 6, lane = tid & 63;
  const int r = lane & 15, g = lane >> 4;

  const int G = wave * 8 + j;                    // q-group (32 rows)
  const int lastA = (G * 32 + 31) >> 6;          // last active kv-iter
  const int nkv = (((56 + j) * 32 + 31) >> 6) + 1;   // block-wide iters

  __shared__ __align__(16) u16 kT[2][64 * 128];
  __shared__ __align__(16) u16 vS[2][128 * 64];
  __shared__ __align__(16) u16 pS[8][32 * 64];

  const size_t headq = (size_t)(b * HEADS + h) * SEQ;
  const u16* kbase = kr + headq * DH;
  const u16* vbase = vT + (size_t)(b * HEADS + h) * DH * SEQ;

  auto stageKV = [&](int buf, int kt) {          // 8 waves: 4 issues/thread
    #pragma unroll
    for (int c = 0; c < 2; ++c) {
      int chunk = (wave * 2 + c) * 64 + lane;    // 0..1023
      int row = chunk >> 4;
      int scolb = ((chunk & 15) << 4) ^ ((row & 7) << 4);
      gload_lds16(kbase + (size_t)(kt * 64 + row) * DH + (scolb >> 1),
                  kT[buf] + (wave * 2 + c) * 64 * 8);
    }
    #pragma unroll
    for (int c = 0; c < 2; ++c) {
      int chunk = (wave * 2 + c) * 64 + lane;
      int d = chunk >> 3;
      int sb = ((chunk & 7) << 4) ^ ((d & 7) << 4);
      gload_lds16(vbase + (size_t)d * SEQ + kt * 64 + (sb >> 1),
                  vS[buf] + (wave * 2 + c) * 64 * 8);
    }
  };

  const f32x4 z4 = {0.f, 0.f, 0.f, 0.f};

  // qf: q rows G*32 + qc*16 + r, d = ks*32 + g*8
  const u16* qbase = qr + (headq + G * 32) * DH;
  bf16x8 qf[2][4];
  #pragma unroll
  for (int qc = 0; qc < 2; ++qc)
    #pragma unroll
    for (int ks = 0; ks < 4; ++ks)
      qf[qc][ks] = *(const bf16x8*)(qbase + (size_t)(qc * 16 + r) * DH +
                                    ks * 32 + g * 8);

  f32x4 o[8][2];
  #pragma unroll
  for (int i = 0; i < 8; ++i) { o[i][0] = z4; o[i][1] = z4; }
  float m[2] = {-3.0e38f, -3.0e38f}, lsum[2] = {0.f, 0.f};

  stageKV(0, 0);
  __syncthreads();

  for (int kt = 0; kt < nkv; ++kt) {
    const int cur = kt & 1;
    if (kt + 1 < nkv) stageKV(cur ^ 1, kt + 1);

    if (kt <= lastA) {                 // wave-uniform guard
      // S^T[kv64][q32]: A = K-frag, B = Q-frag (swapped); s[nt][qc]
      f32x4 s[4][2];
      #pragma unroll
      for (int i = 0; i < 4; ++i) { s[i][0] = z4; s[i][1] = z4; }
      __builtin_amdgcn_s_setprio(1);
      #pragma unroll
      for (int ks = 0; ks < 4; ++ks) {
        #pragma unroll
        for (int nt = 0; nt < 4; ++nt) {
          int krow = nt * 16 + r;
          int koff = krow * 128 + (((ks * 64 + g * 16) ^ ((krow & 7) << 4)) >> 1);
          bf16x8 kf = *(const bf16x8*)&kT[cur][koff];
          s[nt][0] = mfma16(kf, qf[0][ks], s[nt][0]);
          s[nt][1] = mfma16(kf, qf[1][ks], s[nt][1]);
        }
      }
      __builtin_amdgcn_s_setprio(0);

      if (kt == lastA) {               // boundary causal mask
        #pragma unroll
        for (int nt = 0; nt < 4; ++nt)
          #pragma unroll
          for (int qc = 0; qc < 2; ++qc)
            #pragma unroll
            for (int rr = 0; rr < 4; ++rr) {
              int kvloc = kt * 64 + nt * 16 + g * 4 + rr;
              int qloc  = G * 32 + qc * 16 + r;
              if (kvloc > qloc) s[nt][qc][rr] = -1e30f;
            }
      }

      float alpha[2], mnewv[2];
      #pragma unroll
      for (int qc = 0; qc < 2; ++qc) {
        float mx = s[0][qc][0];
        #pragma unroll
        for (int nt = 0; nt < 4; ++nt)
          #pragma unroll
          for (int rr = 0; rr < 4; ++rr)
            mx = fmaxf(mx, s[nt][qc][rr]);
        mx = fmaxf(mx, __shfl_xor(mx, 16));
        mx = fmaxf(mx, __shfl_xor(mx, 32));
        float mnew = fmaxf(m[qc], mx);
        alpha[qc] = exp2f(m[qc] - mnew);
        m[qc] = mnew;
        mnewv[qc] = mnew;
      }

      // exp + running-sum + pack P to LDS in one pass (no p[] array)
      float rs[2] = {0.f, 0.f};
      #pragma unroll
      for (int qc = 0; qc < 2; ++qc) {
        int qrow = qc * 16 + r;
        #pragma unroll
        for (int nt = 0; nt < 4; ++nt) {
          bf16x4 pk;
          #pragma unroll
          for (int rr = 0; rr < 4; ++rr) {
            float pv = exp2f(s[nt][qc][rr] - mnewv[qc]);
            rs[qc] += pv;
            pk[rr] = (short)f2bf(pv);
          }
          int elem = qrow * 64 + ((nt * 16 + g * 4) ^ ((qrow & 7) << 3));
          *(bf16x4*)&pS[wave][elem] = pk;
        }
      }
      #pragma unroll
      for (int qc = 0; qc < 2; ++qc) {
        float t = rs[qc];
        t += __shfl_xor(t, 16);
        t += __shfl_xor(t, 32);
        lsum[qc] = lsum[qc] * alpha[qc] + t;
      }
      #pragma unroll
      for (int dt = 0; dt < 8; ++dt) {
        o[dt][0] *= alpha[0];
        o[dt][1] *= alpha[1];
      }

      // O^T += V(A) x P(B): per ks2 read 2 pf (qc) + 8 vf -> 16 MFMA
      __builtin_amdgcn_s_setprio(1);
      #pragma unroll
      for (int ks2 = 0; ks2 < 2; ++ks2) {
        bf16x8 pf[2];
        #pragma unroll
        for (int qc = 0; qc < 2; ++qc) {
          int prow = qc * 16 + r;
          pf[qc] = *(const bf16x8*)
              &pS[wave][prow * 64 + ((ks2 * 32 + g * 8) ^ ((prow & 7) << 3))];
        }
        #pragma unroll
        for (int dt = 0; dt < 8; ++dt) {
          int vrow = dt * 16 + r;
          int voff = vrow * 64 + (((ks2 * 64 + g * 16) ^ ((vrow & 7) << 4)) >> 1);
          bf16x8 vf = *(const bf16x8*)&vS[cur][voff];
          o[dt][0] = mfma16(vf, pf[0], o[dt][0]);
          o[dt][1] = mfma16(vf, pf[1], o[dt][1]);
        }
      }
      __builtin_amdgcn_s_setprio(0);
    }

    __syncthreads();   // drains prefetch; guards 2-slot reuse
  }

  // epilogue: O^T -> per-wave LDS transpose (own pS region) -> coalesced
  float inv[2] = {1.0f / lsum[0], 1.0f / lsum[1]};
  #pragma unroll
  for (int dh = 0; dh < 2; ++dh) {
    #pragma unroll
    for (int qc = 0; qc < 2; ++qc) {
      int qrow = qc * 16 + r;
      #pragma unroll
      for (int dt4 = 0; dt4 < 4; ++dt4) {
        int dt = dh * 4 + dt4;
        bf16x4 ovp;
        ovp[0] = (short)f2bf(o[dt][qc][0] * inv[qc]);
        ovp[1] = (short)f2bf(o[dt][qc][1] * inv[qc]);
        ovp[2] = (short)f2bf(o[dt][qc][2] * inv[qc]);
        ovp[3] = (short)f2bf(o[dt][qc][3] * inv[qc]);
        int elem = qrow * 64 + ((dt4 * 16 + g * 4) ^ ((qrow & 7) << 3));
        *(bf16x4*)&pS[wave][elem] = ovp;
      }
    }
    #pragma unroll
    for (int i = 0; i < 4; ++i) {      // 32 q x 64 d, uint4 per lane
      int c = i * 64 + lane;
      int qq = c >> 3, dc = c & 7;
      int elem = qq * 64 + ((dc * 8) ^ ((qq & 7) << 3));
      uint4 val = *(const uint4*)&pS[wave][elem];
      *(uint4*)&attn[((size_t)b * SEQ + G * 32 + qq) * INNER +
                     h * DH + dh * 64 + dc * 8] = val;
    }
  }
}

// ---------------- host ----------------
extern "C" void kernel_launch(void* const* d_in, const int* in_sizes, int n_in,
                              void* d_out, int out_size, void* d_ws, size_t ws_size,
                              hipStream_t stream) {
  const float* x   = (const float*)d_in[0];
  const float* rot = (const float*)d_in[1];
  const float* g   = (const float*)d_in[2];
  const float* Wq  = (const float*)d_in[3];
  const float* Wkv = (const float*)d_in[4];
  const float* Wo  = (const float*)d_in[5];

  char* ws = (char*)d_ws;
  size_t off = 0;
  auto alloc = [&](size_t bytes) {
    char* p = ws + off;
    off += (bytes + 255) & ~(size_t)255;
    return p;
  };
  u16*   WqkvT = (u16*)alloc((size_t)6144 * 2048 * 2);  // q rows 0-2047, k 2048-4095, v 4096-6143
  u16*   WoT   = (u16*)alloc((size_t)2048 * 2048 * 2);
  u16*   cosT  = (u16*)alloc((size_t)2048 * 128 * 2);
  u16*   sinT  = (u16*)alloc((size_t)2048 * 128 * 2);
  u16*   xn    = (u16*)alloc((size_t)4096 * 2048 * 2);
  u16*   qkv   = (u16*)alloc((size_t)4096 * 6144 * 2);
  u16*   qr    = (u16*)alloc((size_t)4096 * 2048 * 2);
  // region reuse (dependency-checked against launch order below):
  u16* kr   = WqkvT;  // WqkvT (25.2MB >= 16.8MB) dead after QKV GEMM
  u16* vt   = xn;     // xn dead after QKV GEMM
  u16* attn = qkv;    // qkv dead after rope_q + rope_k + transp_v

  // rope-q scale = 1/sqrt(128) * log2(e)  (softmax runs in exp2 domain)
  const float qscale = 0.08838834764831845f * 1.4426950408889634f;

  transpose_cast<<<dim3(1024), 256, 0, stream>>>(Wq,  WqkvT,               2048, 2048);
  transpose_cast<<<dim3(2048), 256, 0, stream>>>(Wkv, WqkvT + 2048 * 2048, 2048, 4096);
  transpose_cast<<<dim3(1024), 256, 0, stream>>>(Wo,  WoT,                 2048, 2048);
  build_tables<<<dim3(2048 * 128 / 256), 256, 0, stream>>>(rot, cosT, sinT);
  rmsnorm_k<<<dim3(4096), 256, 0, stream>>>(x, g, xn);
  gemm_qkv<<<dim3(768), 512, 0, stream>>>(xn, WqkvT, qkv, 4096, 6144, 2048);
  rope_rearrange<<<dim3(2048), 256, 0, stream>>>(qkv,        6144, cosT, sinT, qr, qscale);
  rope_rearrange<<<dim3(2048), 256, 0, stream>>>(qkv + 2048, 6144, cosT, sinT, kr, 1.0f);
  transp_v<<<dim3(2048), 256, 0, stream>>>(qkv + 4096, 6144, vt);
  flash<<<dim3(256), 512, 0, stream>>>(qr, kr, vt, attn);
  gemm128<1><<<dim3(512), 256, 0, stream>>>(attn, WoT, (float*)d_out, 4096, 2048, 2048);
}

// Round 14
// 300.261 us; speedup vs baseline: 1.0337x; 1.0337x over previous
//
#include <hip/hip_runtime.h>
#include <cstdint>
#include <cstddef>

#define DIM    2048
#define HEADS  16
#define DH     128
#define INNER  2048
#define SEQ    2048
#define BATCH  2
#define NTOK   4096

typedef unsigned short u16;
typedef __attribute__((ext_vector_type(4))) short bf16x4;
typedef __attribute__((ext_vector_type(8))) short bf16x8;
typedef __attribute__((ext_vector_type(4))) float f32x4;

__device__ __forceinline__ u16 f2bf(float f) {
  union { float f; unsigned u; } v; v.f = f;
  unsigned r = v.u + 0x7FFFu + ((v.u >> 16) & 1u);
  return (u16)(r >> 16);
}
__device__ __forceinline__ float bf2f(u16 h) {
  union { unsigned u; float f; } v; v.u = ((unsigned)h) << 16;
  return v.f;
}

using as1_t = __attribute__((address_space(1))) const void;
using as3_t = __attribute__((address_space(3))) void;
__device__ __forceinline__ void gload_lds16(const void* g, void* l) {
  __builtin_amdgcn_global_load_lds((as1_t*)g, (as3_t*)l, 16, 0, 0);
}

__device__ __forceinline__ f32x4 mfma16(bf16x8 a, bf16x8 b, f32x4 c) {
  return __builtin_amdgcn_mfma_f32_16x16x32_bf16(a, b, c, 0, 0, 0);
}

// ---------------- weight transpose + cast, vectorized: W[K][N] -> Wt[N][K] -
__global__ __launch_bounds__(256)
void transpose_cast(const float* __restrict__ W, u16* __restrict__ Wt,
                    int K, int N) {
  __shared__ float t[64][65];
  const int tiles_n = N >> 6;
  const int tx = blockIdx.x % tiles_n, ty = blockIdx.x / tiles_n;
  const int tid = threadIdx.x;
  const int k0 = ty << 6, n0 = tx << 6;
  #pragma unroll
  for (int i = 0; i < 4; ++i) {       // 64 k-rows x 16 float4
    int e = tid + i * 256;
    int kr = e >> 4, c4 = e & 15;
    *(float4*)&t[kr][c4 * 4] =
        *(const float4*)&W[(size_t)(k0 + kr) * N + n0 + c4 * 4];
  }
  __syncthreads();
  #pragma unroll
  for (int i = 0; i < 2; ++i) {       // 64 n-rows x 8 k8-chunks
    int e = tid + i * 256;
    int nr = e >> 3, k8 = e & 7;
    u16 o[8];
    #pragma unroll
    for (int j = 0; j < 8; ++j) o[j] = f2bf(t[k8 * 8 + j][nr]);
    *(uint4*)&Wt[(size_t)(n0 + nr) * K + k0 + k8 * 8] = *(const uint4*)o;
  }
}

// ---------------- rope cos/sin tables (bf16) ----------------
__global__ __launch_bounds__(256)
void build_tables(const float* __restrict__ rot, u16* __restrict__ cosT,
                  u16* __restrict__ sinT) {
  int i = blockIdx.x * 256 + threadIdx.x;
  float v = rot[i];
  cosT[i] = f2bf(cosf(v));
  sinT[i] = f2bf(sinf(v));
}

// ---------------- RMSNorm: x f32 [NTOK][DIM] -> xn bf16 ----------------
__global__ __launch_bounds__(256)
void rmsnorm_k(const float* __restrict__ x, const float* __restrict__ gw,
               u16* __restrict__ xn) {
  const int row = blockIdx.x, tid = threadIdx.x;
  const float4* x4 = (const float4*)(x + (size_t)row * DIM);
  float4 a = x4[tid * 2], b = x4[tid * 2 + 1];
  float ss = a.x*a.x + a.y*a.y + a.z*a.z + a.w*a.w
           + b.x*b.x + b.y*b.y + b.z*b.z + b.w*b.w;
  #pragma unroll
  for (int off = 1; off < 64; off <<= 1) ss += __shfl_xor(ss, off);
  __shared__ float red[4];
  if ((tid & 63) == 0) red[tid >> 6] = ss;
  __syncthreads();
  float tot = red[0] + red[1] + red[2] + red[3];
  float sc = 1.0f / fmaxf(sqrtf(tot * (1.0f / DIM)), 1e-8f);
  const float4* g4 = (const float4*)gw;
  float4 ga = g4[tid * 2], gb = g4[tid * 2 + 1];
  u16 ov[8];
  ov[0] = f2bf(a.x * sc * ga.x); ov[1] = f2bf(a.y * sc * ga.y);
  ov[2] = f2bf(a.z * sc * ga.z); ov[3] = f2bf(a.w * sc * ga.w);
  ov[4] = f2bf(b.x * sc * gb.x); ov[5] = f2bf(b.y * sc * gb.y);
  ov[6] = f2bf(b.z * sc * gb.z); ov[7] = f2bf(b.w * sc * gb.w);
  *(uint4*)(xn + (size_t)row * DIM + tid * 8) = *(const uint4*)ov;
}

// ---------------- fused QKV GEMM: 128x256, 2-slot dbuf, 2 blocks/CU -------
// (R8 config, banked best: ~130us / MfmaUtil 34.5 / 0 conflicts. PARKED.)
__global__ __launch_bounds__(512, 4)
void gemm_qkv(const u16* __restrict__ A, const u16* __restrict__ Bt,
              u16* __restrict__ C, int M, int N, int K) {
  __shared__ __align__(16) u16 lA[2][128 * 32];
  __shared__ __align__(16) u16 lB[2][256 * 32];
  const int tid = threadIdx.x;
  const int wave = tid >> 6, lane = tid & 63;
  const int r = lane & 15, g = lane >> 4;
  const int wr = wave >> 2, wc = wave & 3;   // 2M x 4N wave grid

  const int bid = blockIdx.x;
  const int wg = (bid & 7) * 96 + (bid >> 3);   // XCD-chunked, 768%8==0
  const int mtile = wg & 31;                    // inner: A panel streams
  const int ntile = wg >> 5;                    // 0..23: B panel L2-resident

  const u16* Abase = A + (size_t)mtile * 128 * K;
  const u16* Bbase = Bt + (size_t)ntile * 256 * K;
  const int nk = K >> 5;   // 64 K-tiles

  auto stA = [&](int j) {            // 8 KB: 1 issue/thread
    int kk = j << 5;
    int row = tid >> 2;
    int col = ((tid & 3) ^ ((row >> 1) & 3)) << 3;
    gload_lds16(Abase + (size_t)row * K + kk + col, &lA[j & 1][wave * 512]);
  };
  auto stB = [&](int j) {            // 16 KB: 2 issues/thread
    int kk = j << 5;
    #pragma unroll
    for (int c = 0; c < 2; ++c) {
      int chunk = c * 512 + tid;
      int row = chunk >> 2;
      int col = ((chunk & 3) ^ ((row >> 1) & 3)) << 3;
      gload_lds16(Bbase + (size_t)row * K + kk + col,
                  &lB[j & 1][c * 4096 + wave * 512]);
    }
  };

  f32x4 acc[4][4];
  const f32x4 z4 = {0.f, 0.f, 0.f, 0.f};
  #pragma unroll
  for (int i = 0; i < 4; ++i)
    #pragma unroll
    for (int j = 0; j < 4; ++j) acc[i][j] = z4;

  const int sw8 = ((g ^ ((r >> 1) & 3)) << 3);
  const int laneA = (wr * 64 + r) * 32 + sw8;
  const int laneB = (wc * 64 + r) * 32 + sw8;

  stA(0); stB(0);
  asm volatile("s_waitcnt vmcnt(0)" ::: "memory");
  __builtin_amdgcn_s_barrier();

  for (int j = 0; j < nk; ++j) {
    if (j + 1 < nk) { stA(j + 1); stB(j + 1); }   // writes slot (j+1)&1
    const u16* bA = &lA[j & 1][0];
    const u16* bB = &lB[j & 1][0];
    bf16x8 af[4], bf[4];
    #pragma unroll
    for (int mi = 0; mi < 4; ++mi)
      af[mi] = *(const bf16x8*)&bA[laneA + mi * 512];
    #pragma unroll
    for (int ni = 0; ni < 4; ++ni)
      bf[ni] = *(const bf16x8*)&bB[laneB + ni * 512];
    __builtin_amdgcn_s_setprio(1);
    #pragma unroll
    for (int mi = 0; mi < 4; ++mi)
      #pragma unroll
      for (int ni = 0; ni < 4; ++ni)
        acc[mi][ni] = mfma16(af[mi], bf[ni], acc[mi][ni]);
    __builtin_amdgcn_s_setprio(0);
    asm volatile("s_waitcnt vmcnt(0)" ::: "memory");  // drain prefetch j+1
    __builtin_amdgcn_s_barrier();                     // all reads of slot done
  }

  #pragma unroll
  for (int mi = 0; mi < 4; ++mi)
    #pragma unroll
    for (int ni = 0; ni < 4; ++ni)
      #pragma unroll
      for (int rr = 0; rr < 4; ++rr) {
        int row = mtile * 128 + wr * 64 + mi * 16 + g * 4 + rr;
        int col = ntile * 256 + wc * 64 + ni * 16 + r;
        C[(size_t)row * N + col] = f2bf(acc[mi][ni][rr]);
      }
}

// ---------------- GEMM 128x128 (O-projection), XCD-chunked flat grid ------
template<int F32OUT>
__global__ __launch_bounds__(256, 3)
void gemm128(const u16* __restrict__ A, const u16* __restrict__ Bt,
             void* __restrict__ C, int M, int N, int K) {
  const int tid = threadIdx.x;
  const int wave = tid >> 6, lane = tid & 63;
  const int bid = blockIdx.x;
  const int wg = (bid & 7) * (gridDim.x >> 3) + (bid >> 3);  // XCD-chunked
  const int mt = wg & 31, nt0 = wg >> 5;
  __shared__ __align__(16) u16 ldsA[2][128 * 32];
  __shared__ __align__(16) u16 ldsB[2][128 * 32];

  const int wm = (wave >> 1) * 64, wn = (wave & 1) * 64;
  const int r = lane & 15, g = lane >> 4;

  f32x4 acc[4][4];
  const f32x4 z4 = {0.f, 0.f, 0.f, 0.f};
  #pragma unroll
  for (int i = 0; i < 4; ++i)
    #pragma unroll
    for (int j = 0; j < 4; ++j) acc[i][j] = z4;

  const u16* Abase = A + (size_t)mt * 128 * K;
  const u16* Bbase = Bt + (size_t)nt0 * 128 * K;

  auto stage = [&](u16* dst, const u16* src, int kb) {
    #pragma unroll
    for (int c = 0; c < 2; ++c) {
      int chunk = wave * 128 + c * 64 + lane;
      int row = chunk >> 2;
      int colb = (chunk & 3) << 4;
      int scolb = colb ^ (((row >> 1) & 3) << 4);
      gload_lds16(src + (size_t)row * K + kb + (scolb >> 1),
                  dst + (wave * 128 + c * 64) * 8);
    }
  };

  const int nk = K >> 5;
  stage(ldsA[0], Abase, 0);
  stage(ldsB[0], Bbase, 0);
  __syncthreads();

  for (int kt = 0; kt < nk; ++kt) {
    const int cur = kt & 1;
    if (kt + 1 < nk) {
      stage(ldsA[cur ^ 1], Abase, (kt + 1) << 5);
      stage(ldsB[cur ^ 1], Bbase, (kt + 1) << 5);
    }
    bf16x8 af[4], bfr[4];
    #pragma unroll
    for (int mi = 0; mi < 4; ++mi) {
      int row = wm + mi * 16 + r;
      int off = row * 32 + (((g << 4) ^ (((row >> 1) & 3) << 4)) >> 1);
      af[mi] = *(const bf16x8*)&ldsA[cur][off];
    }
    #pragma unroll
    for (int ni = 0; ni < 4; ++ni) {
      int row = wn + ni * 16 + r;
      int off = row * 32 + (((g << 4) ^ (((row >> 1) & 3) << 4)) >> 1);
      bfr[ni] = *(const bf16x8*)&ldsB[cur][off];
    }
    __builtin_amdgcn_s_setprio(1);
    #pragma unroll
    for (int mi = 0; mi < 4; ++mi)
      #pragma unroll
      for (int ni = 0; ni < 4; ++ni)
        acc[mi][ni] = mfma16(af[mi], bfr[ni], acc[mi][ni]);
    __builtin_amdgcn_s_setprio(0);
    __syncthreads();
  }

  #pragma unroll
  for (int mi = 0; mi < 4; ++mi)
    #pragma unroll
    for (int ni = 0; ni < 4; ++ni)
      #pragma unroll
      for (int rr = 0; rr < 4; ++rr) {
        int row = mt * 128 + wm + mi * 16 + g * 4 + rr;
        int col = nt0 * 128 + wn + ni * 16 + r;
        float v = acc[mi][ni][rr];
        if (F32OUT) ((float*)C)[(size_t)row * N + col] = v;
        else        ((u16*)C)[(size_t)row * N + col] = f2bf(v);
      }
}

// ---------------- RoPE + rearrange (vectorized 8/thread) ------------------
__global__ __launch_bounds__(256)
void rope_rearrange(const u16* __restrict__ src, int ldsrc,
                    const u16* __restrict__ cosT, const u16* __restrict__ sinT,
                    u16* __restrict__ dst, float scale) {
  int id = blockIdx.x * 256 + threadIdx.x;
  int c8 = id & 7;               // 8-elem chunk within [0,64)
  int hh = (id >> 3) & 15;
  int tok = id >> 7;             // 0..32767
  int n = tok & (SEQ - 1);
  int b = tok >> 11;
  const u16* s = src + (size_t)tok * ldsrc + hh * DH + c8 * 8;
  uint4 d1 = *(const uint4*)s;
  uint4 d2 = *(const uint4*)(s + 64);
  const u16* ct = cosT + n * DH + c8 * 8;
  const u16* st = sinT + n * DH + c8 * 8;
  uint4 c1 = *(const uint4*)ct, c2 = *(const uint4*)(ct + 64);
  uint4 s1 = *(const uint4*)st, s2 = *(const uint4*)(st + 64);
  const u16* d1p = (const u16*)&d1; const u16* d2p = (const u16*)&d2;
  const u16* c1p = (const u16*)&c1; const u16* c2p = (const u16*)&c2;
  const u16* s1p = (const u16*)&s1; const u16* s2p = (const u16*)&s2;
  u16 o1[8], o2[8];
  #pragma unroll
  for (int i = 0; i < 8; ++i) {
    float t1 = bf2f(d1p[i]), t2 = bf2f(d2p[i]);
    o1[i] = f2bf((t1 * bf2f(c1p[i]) - t2 * bf2f(s1p[i])) * scale);
    o2[i] = f2bf((t2 * bf2f(c2p[i]) + t1 * bf2f(s2p[i])) * scale);
  }
  u16* dp = dst + ((size_t)(b * HEADS + hh) * SEQ + n) * DH + c8 * 8;
  *(uint4*)dp = *(const uint4*)o1;
  *(uint4*)(dp + 64) = *(const uint4*)o2;
}

// ---------------- V transpose: v0[NTOK][ld] -> vT[B][H][DH][SEQ] ----------
__global__ __launch_bounds__(256)
void transp_v(const u16* __restrict__ v0, int ld, u16* __restrict__ vTo) {
  __shared__ __align__(16) u16 t[32][136];
  const int id = blockIdx.x;
  const int ntile = id & 63;
  const int hh = (id >> 6) & 15;
  const int b = id >> 10;
  const int tid = threadIdx.x;
  const int n0 = ntile * 32;
  #pragma unroll
  for (int it = 0; it < 2; ++it) {
    int chunk = it * 256 + tid;
    int nr = chunk >> 4, dc = chunk & 15;
    const u16* src = v0 + (size_t)(b * SEQ + n0 + nr) * ld + hh * DH + dc * 8;
    *(uint4*)&t[nr][dc * 8] = *(const uint4*)src;
  }
  __syncthreads();
  int d = tid >> 1, nh = tid & 1;
  u16 tmp[16];
  #pragma unroll
  for (int j = 0; j < 16; ++j) tmp[j] = t[nh * 16 + j][d];
  u16* dst = vTo + ((size_t)(b * HEADS + hh) * DH + d) * SEQ + n0 + nh * 16;
  *(uint4*)&dst[0] = *(const uint4*)&tmp[0];
  *(uint4*)&dst[8] = *(const uint4*)&tmp[8];
}

// ---------------- flash attention (causal), 4 waves x 32 q-rows ----------
// Synthesis of the two confirmed mechanisms:
//  - R12 geometry: 4-wave blocks, 512 blocks -> 2 blocks/CU (independent
//    barrier domains), all waves share one q-tile -> no guard idling
//    (except the single boundary iter for waves 0-1).
//  - R13 density: 32 q-rows/wave -> K/V tile reads feed 64 MFMA instead of
//    32 (reads/MFMA 1.06 -> 0.56 on the binding LDS-read resource).
// Block = 128 contiguous q-rows (tile qt of 16/head). Mapping gives blocks
// c and c+256 (typically co-resident across dispatch rounds) complementary
// tiles {t,15-t} of the SAME head -> ~34 uniform iters/CU; T1: 4 heads/XCD.
// LDS 80 KB (kT 32 + vS 32 + pS 16) -> 2x80 = 160 KB exact CU fit.
__global__ __launch_bounds__(256, 2)
void flash(const u16* __restrict__ qr, const u16* __restrict__ kr,
           const u16* __restrict__ vT, u16* __restrict__ attn) {
  const int bid = blockIdx.x;
  const int u = (bid & 7) * 64 + (bid >> 3);     // XCD-major remap, 512%8==0
  const int xcd = u >> 6, y = u & 63;
  const int hb = xcd * 4 + (y & 3);              // 4 heads per XCD
  const int h = hb & 15, b = hb >> 4;
  const int tr = y >> 2;                         // 0..15
  const int qt = (y < 32) ? tr : (23 - tr);      // paired {t, 15-t}
  const int tid = threadIdx.x, wave = tid >> 6, lane = tid & 63;
  const int r = lane & 15, g = lane >> 4;

  const int qrow0 = qt * 128 + wave * 32;        // wave's 32 q-rows
  const int lastA = (qrow0 + 31) >> 6;           // last active kv-iter
  const int nkv = 2 * qt + 2;                    // block-wide kv-iters

  __shared__ __align__(16) u16 kT[2][64 * 128];
  __shared__ __align__(16) u16 vS[2][128 * 64];
  __shared__ __align__(16) u16 pS[4][32 * 64];

  const size_t headq = (size_t)(b * HEADS + h) * SEQ;
  const u16* kbase = kr + headq * DH;
  const u16* vbase = vT + (size_t)(b * HEADS + h) * DH * SEQ;

  auto stageKV = [&](int buf, int kt) {        // 8 issues/thread (K:4, V:4)
    #pragma unroll
    for (int c = 0; c < 4; ++c) {
      int chunk = (wave * 4 + c) * 64 + lane;          // 0..1023
      int row = chunk >> 4;
      int scolb = ((chunk & 15) << 4) ^ ((row & 7) << 4);
      gload_lds16(kbase + (size_t)(kt * 64 + row) * DH + (scolb >> 1),
                  kT[buf] + (wave * 4 + c) * 64 * 8);
    }
    #pragma unroll
    for (int c = 0; c < 4; ++c) {
      int chunk = (wave * 4 + c) * 64 + lane;
      int d = chunk >> 3;
      int sb = ((chunk & 7) << 4) ^ ((d & 7) << 4);
      gload_lds16(vbase + (size_t)d * SEQ + kt * 64 + (sb >> 1),
                  vS[buf] + (wave * 4 + c) * 64 * 8);
    }
  };

  const f32x4 z4 = {0.f, 0.f, 0.f, 0.f};

  // qf: q rows qrow0 + qc*16 + r, d = ks*32 + g*8
  const u16* qbase = qr + (headq + qrow0) * DH;
  bf16x8 qf[2][4];
  #pragma unroll
  for (int qc = 0; qc < 2; ++qc)
    #pragma unroll
    for (int ks = 0; ks < 4; ++ks)
      qf[qc][ks] = *(const bf16x8*)(qbase + (size_t)(qc * 16 + r) * DH +
                                    ks * 32 + g * 8);

  f32x4 o[8][2];
  #pragma unroll
  for (int i = 0; i < 8; ++i) { o[i][0] = z4; o[i][1] = z4; }
  float m[2] = {-3.0e38f, -3.0e38f}, lsum[2] = {0.f, 0.f};

  stageKV(0, 0);
  __syncthreads();

  for (int kt = 0; kt < nkv; ++kt) {
    const int cur = kt & 1;
    if (kt + 1 < nkv) stageKV(cur ^ 1, kt + 1);

    if (kt <= lastA) {               // wave-uniform; idle only boundary iter
      // S^T[kv64][q32]: A = K-frag, B = Q-frag (swapped); s[nt][qc]
      f32x4 s[4][2];
      #pragma unroll
      for (int i = 0; i < 4; ++i) { s[i][0] = z4; s[i][1] = z4; }
      __builtin_amdgcn_s_setprio(1);
      #pragma unroll
      for (int ks = 0; ks < 4; ++ks) {
        #pragma unroll
        for (int nt = 0; nt < 4; ++nt) {
          int krow = nt * 16 + r;
          int koff = krow * 128 + (((ks * 64 + g * 16) ^ ((krow & 7) << 4)) >> 1);
          bf16x8 kf = *(const bf16x8*)&kT[cur][koff];
          s[nt][0] = mfma16(kf, qf[0][ks], s[nt][0]);
          s[nt][1] = mfma16(kf, qf[1][ks], s[nt][1]);
        }
      }
      __builtin_amdgcn_s_setprio(0);

      if (kt == lastA) {             // boundary causal mask
        #pragma unroll
        for (int nt = 0; nt < 4; ++nt)
          #pragma unroll
          for (int qc = 0; qc < 2; ++qc)
            #pragma unroll
            for (int rr = 0; rr < 4; ++rr) {
              int kvloc = kt * 64 + nt * 16 + g * 4 + rr;
              int qloc  = qrow0 + qc * 16 + r;
              if (kvloc > qloc) s[nt][qc][rr] = -1e30f;
            }
      }

      float alpha[2], mnewv[2];
      #pragma unroll
      for (int qc = 0; qc < 2; ++qc) {
        float mx = s[0][qc][0];
        #pragma unroll
        for (int nt = 0; nt < 4; ++nt)
          #pragma unroll
          for (int rr = 0; rr < 4; ++rr)
            mx = fmaxf(mx, s[nt][qc][rr]);
        mx = fmaxf(mx, __shfl_xor(mx, 16));
        mx = fmaxf(mx, __shfl_xor(mx, 32));
        float mnew = fmaxf(m[qc], mx);
        alpha[qc] = exp2f(m[qc] - mnew);
        m[qc] = mnew;
        mnewv[qc] = mnew;
      }

      // exp + running-sum + pack P to LDS in one pass
      float rs[2] = {0.f, 0.f};
      #pragma unroll
      for (int qc = 0; qc < 2; ++qc) {
        int qrow = qc * 16 + r;
        #pragma unroll
        for (int nt = 0; nt < 4; ++nt) {
          bf16x4 pk;
          #pragma unroll
          for (int rr = 0; rr < 4; ++rr) {
            float pv = exp2f(s[nt][qc][rr] - mnewv[qc]);
            rs[qc] += pv;
            pk[rr] = (short)f2bf(pv);
          }
          int elem = qrow * 64 + ((nt * 16 + g * 4) ^ ((qrow & 7) << 3));
          *(bf16x4*)&pS[wave][elem] = pk;
        }
      }
      #pragma unroll
      for (int qc = 0; qc < 2; ++qc) {
        float t = rs[qc];
        t += __shfl_xor(t, 16);
        t += __shfl_xor(t, 32);
        lsum[qc] = lsum[qc] * alpha[qc] + t;
      }
      #pragma unroll
      for (int dt = 0; dt < 8; ++dt) {
        o[dt][0] *= alpha[0];
        o[dt][1] *= alpha[1];
      }

      // O^T += V(A) x P(B): per ks2 read 2 pf + 8 vf -> 16 MFMA
      __builtin_amdgcn_s_setprio(1);
      #pragma unroll
      for (int ks2 = 0; ks2 < 2; ++ks2) {
        bf16x8 pf[2];
        #pragma unroll
        for (int qc = 0; qc < 2; ++qc) {
          int prow = qc * 16 + r;
          pf[qc] = *(const bf16x8*)
              &pS[wave][prow * 64 + ((ks2 * 32 + g * 8) ^ ((prow & 7) << 3))];
        }
        #pragma unroll
        for (int dt = 0; dt < 8; ++dt) {
          int vrow = dt * 16 + r;
          int voff = vrow * 64 + (((ks2 * 64 + g * 16) ^ ((vrow & 7) << 4)) >> 1);
          bf16x8 vf = *(const bf16x8*)&vS[cur][voff];
          o[dt][0] = mfma16(vf, pf[0], o[dt][0]);
          o[dt][1] = mfma16(vf, pf[1], o[dt][1]);
        }
      }
      __builtin_amdgcn_s_setprio(0);
    }

    __syncthreads();   // drains prefetch; guards 2-slot reuse
  }

  // epilogue: O^T -> per-wave LDS transpose (own pS region) -> coalesced
  float inv[2] = {1.0f / lsum[0], 1.0f / lsum[1]};
  #pragma unroll
  for (int dh = 0; dh < 2; ++dh) {
    #pragma unroll
    for (int qc = 0; qc < 2; ++qc) {
      int qrow = qc * 16 + r;
      #pragma unroll
      for (int dt4 = 0; dt4 < 4; ++dt4) {
        int dt = dh * 4 + dt4;
        bf16x4 ovp;
        ovp[0] = (short)f2bf(o[dt][qc][0] * inv[qc]);
        ovp[1] = (short)f2bf(o[dt][qc][1] * inv[qc]);
        ovp[2] = (short)f2bf(o[dt][qc][2] * inv[qc]);
        ovp[3] = (short)f2bf(o[dt][qc][3] * inv[qc]);
        int elem = qrow * 64 + ((dt4 * 16 + g * 4) ^ ((qrow & 7) << 3));
        *(bf16x4*)&pS[wave][elem] = ovp;
      }
    }
    #pragma unroll
    for (int i = 0; i < 4; ++i) {      // 32 q x 64 d, uint4 per lane
      int c = i * 64 + lane;
      int qq = c >> 3, dc = c & 7;
      int elem = qq * 64 + ((dc * 8) ^ ((qq & 7) << 3));
      uint4 val = *(const uint4*)&pS[wave][elem];
      *(uint4*)&attn[((size_t)b * SEQ + qrow0 + qq) * INNER +
                     h * DH + dh * 64 + dc * 8] = val;
    }
  }
}

// ---------------- host ----------------
extern "C" void kernel_launch(void* const* d_in, const int* in_sizes, int n_in,
                              void* d_out, int out_size, void* d_ws, size_t ws_size,
                              hipStream_t stream) {
  const float* x   = (const float*)d_in[0];
  const float* rot = (const float*)d_in[1];
  const float* g   = (const float*)d_in[2];
  const float* Wq  = (const float*)d_in[3];
  const float* Wkv = (const float*)d_in[4];
  const float* Wo  = (const float*)d_in[5];

  char* ws = (char*)d_ws;
  size_t off = 0;
  auto alloc = [&](size_t bytes) {
    char* p = ws + off;
    off += (bytes + 255) & ~(size_t)255;
    return p;
  };
  u16*   WqkvT = (u16*)alloc((size_t)6144 * 2048 * 2);  // q rows 0-2047, k 2048-4095, v 4096-6143
  u16*   WoT   = (u16*)alloc((size_t)2048 * 2048 * 2);
  u16*   cosT  = (u16*)alloc((size_t)2048 * 128 * 2);
  u16*   sinT  = (u16*)alloc((size_t)2048 * 128 * 2);
  u16*   xn    = (u16*)alloc((size_t)4096 * 2048 * 2);
  u16*   qkv   = (u16*)alloc((size_t)4096 * 6144 * 2);
  u16*   qr    = (u16*)alloc((size_t)4096 * 2048 * 2);
  // region reuse (dependency-checked against launch order below):
  u16* kr   = WqkvT;  // WqkvT (25.2MB >= 16.8MB) dead after QKV GEMM
  u16* vt   = xn;     // xn dead after QKV GEMM
  u16* attn = qkv;    // qkv dead after rope_q + rope_k + transp_v

  // rope-q scale = 1/sqrt(128) * log2(e)  (softmax runs in exp2 domain)
  const float qscale = 0.08838834764831845f * 1.4426950408889634f;

  transpose_cast<<<dim3(1024), 256, 0, stream>>>(Wq,  WqkvT,               2048, 2048);
  transpose_cast<<<dim3(2048), 256, 0, stream>>>(Wkv, WqkvT + 2048 * 2048, 2048, 4096);
  transpose_cast<<<dim3(1024), 256, 0, stream>>>(Wo,  WoT,                 2048, 2048);
  build_tables<<<dim3(2048 * 128 / 256), 256, 0, stream>>>(rot, cosT, sinT);
  rmsnorm_k<<<dim3(4096), 256, 0, stream>>>(x, g, xn);
  gemm_qkv<<<dim3(768), 512, 0, stream>>>(xn, WqkvT, qkv, 4096, 6144, 2048);
  rope_rearrange<<<dim3(2048), 256, 0, stream>>>(qkv,        6144, cosT, sinT, qr, qscale);
  rope_rearrange<<<dim3(2048), 256, 0, stream>>>(qkv + 2048, 6144, cosT, sinT, kr, 1.0f);
  transp_v<<<dim3(2048), 256, 0, stream>>>(qkv + 4096, 6144, vt);
  flash<<<dim3(512), 256, 0, stream>>>(qr, kr, vt, attn);
  gemm128<1><<<dim3(512), 256, 0, stream>>>(attn, WoT, (float*)d_out, 4096, 2048, 2048);
}

// Round 15
// 291.012 us; speedup vs baseline: 1.0665x; 1.0318x over previous
//
#include <hip/hip_runtime.h>
#include <cstdint>
#include <cstddef>

#define DIM    2048
#define HEADS  16
#define DH     128
#define INNER  2048
#define SEQ    2048
#define BATCH  2
#define NTOK   4096

typedef unsigned short u16;
typedef __attribute__((ext_vector_type(4))) short bf16x4;
typedef __attribute__((ext_vector_type(8))) short bf16x8;
typedef __attribute__((ext_vector_type(4))) float f32x4;

__device__ __forceinline__ u16 f2bf(float f) {
  union { float f; unsigned u; } v; v.f = f;
  unsigned r = v.u + 0x7FFFu + ((v.u >> 16) & 1u);
  return (u16)(r >> 16);
}
__device__ __forceinline__ float bf2f(u16 h) {
  union { unsigned u; float f; } v; v.u = ((unsigned)h) << 16;
  return v.f;
}

using as1_t = __attribute__((address_space(1))) const void;
using as3_t = __attribute__((address_space(3))) void;
__device__ __forceinline__ void gload_lds16(const void* g, void* l) {
  __builtin_amdgcn_global_load_lds((as1_t*)g, (as3_t*)l, 16, 0, 0);
}

__device__ __forceinline__ f32x4 mfma16(bf16x8 a, bf16x8 b, f32x4 c) {
  return __builtin_amdgcn_mfma_f32_16x16x32_bf16(a, b, c, 0, 0, 0);
}

// ---------------- weight transpose + cast, vectorized: W[K][N] -> Wt[N][K] -
__global__ __launch_bounds__(256)
void transpose_cast(const float* __restrict__ W, u16* __restrict__ Wt,
                    int K, int N) {
  __shared__ float t[64][65];
  const int tiles_n = N >> 6;
  const int tx = blockIdx.x % tiles_n, ty = blockIdx.x / tiles_n;
  const int tid = threadIdx.x;
  const int k0 = ty << 6, n0 = tx << 6;
  #pragma unroll
  for (int i = 0; i < 4; ++i) {       // 64 k-rows x 16 float4
    int e = tid + i * 256;
    int kr = e >> 4, c4 = e & 15;
    *(float4*)&t[kr][c4 * 4] =
        *(const float4*)&W[(size_t)(k0 + kr) * N + n0 + c4 * 4];
  }
  __syncthreads();
  #pragma unroll
  for (int i = 0; i < 2; ++i) {       // 64 n-rows x 8 k8-chunks
    int e = tid + i * 256;
    int nr = e >> 3, k8 = e & 7;
    u16 o[8];
    #pragma unroll
    for (int j = 0; j < 8; ++j) o[j] = f2bf(t[k8 * 8 + j][nr]);
    *(uint4*)&Wt[(size_t)(n0 + nr) * K + k0 + k8 * 8] = *(const uint4*)o;
  }
}

// ---------------- rope cos/sin tables (bf16) ----------------
__global__ __launch_bounds__(256)
void build_tables(const float* __restrict__ rot, u16* __restrict__ cosT,
                  u16* __restrict__ sinT) {
  int i = blockIdx.x * 256 + threadIdx.x;
  float v = rot[i];
  cosT[i] = f2bf(cosf(v));
  sinT[i] = f2bf(sinf(v));
}

// ---------------- RMSNorm: x f32 [NTOK][DIM] -> xn bf16 ----------------
__global__ __launch_bounds__(256)
void rmsnorm_k(const float* __restrict__ x, const float* __restrict__ gw,
               u16* __restrict__ xn) {
  const int row = blockIdx.x, tid = threadIdx.x;
  const float4* x4 = (const float4*)(x + (size_t)row * DIM);
  float4 a = x4[tid * 2], b = x4[tid * 2 + 1];
  float ss = a.x*a.x + a.y*a.y + a.z*a.z + a.w*a.w
           + b.x*b.x + b.y*b.y + b.z*b.z + b.w*b.w;
  #pragma unroll
  for (int off = 1; off < 64; off <<= 1) ss += __shfl_xor(ss, off);
  __shared__ float red[4];
  if ((tid & 63) == 0) red[tid >> 6] = ss;
  __syncthreads();
  float tot = red[0] + red[1] + red[2] + red[3];
  float sc = 1.0f / fmaxf(sqrtf(tot * (1.0f / DIM)), 1e-8f);
  const float4* g4 = (const float4*)gw;
  float4 ga = g4[tid * 2], gb = g4[tid * 2 + 1];
  u16 ov[8];
  ov[0] = f2bf(a.x * sc * ga.x); ov[1] = f2bf(a.y * sc * ga.y);
  ov[2] = f2bf(a.z * sc * ga.z); ov[3] = f2bf(a.w * sc * ga.w);
  ov[4] = f2bf(b.x * sc * gb.x); ov[5] = f2bf(b.y * sc * gb.y);
  ov[6] = f2bf(b.z * sc * gb.z); ov[7] = f2bf(b.w * sc * gb.w);
  *(uint4*)(xn + (size_t)row * DIM + tid * 8) = *(const uint4*)ov;
}

// ---------------- fused QKV GEMM: 128x256, 2-slot dbuf, 2 blocks/CU -------
// (R8 config, banked best: ~130us / MfmaUtil 34.5 / 0 conflicts. PARKED.)
__global__ __launch_bounds__(512, 4)
void gemm_qkv(const u16* __restrict__ A, const u16* __restrict__ Bt,
              u16* __restrict__ C, int M, int N, int K) {
  __shared__ __align__(16) u16 lA[2][128 * 32];
  __shared__ __align__(16) u16 lB[2][256 * 32];
  const int tid = threadIdx.x;
  const int wave = tid >> 6, lane = tid & 63;
  const int r = lane & 15, g = lane >> 4;
  const int wr = wave >> 2, wc = wave & 3;   // 2M x 4N wave grid

  const int bid = blockIdx.x;
  const int wg = (bid & 7) * 96 + (bid >> 3);   // XCD-chunked, 768%8==0
  const int mtile = wg & 31;                    // inner: A panel streams
  const int ntile = wg >> 5;                    // 0..23: B panel L2-resident

  const u16* Abase = A + (size_t)mtile * 128 * K;
  const u16* Bbase = Bt + (size_t)ntile * 256 * K;
  const int nk = K >> 5;   // 64 K-tiles

  auto stA = [&](int j) {            // 8 KB: 1 issue/thread
    int kk = j << 5;
    int row = tid >> 2;
    int col = ((tid & 3) ^ ((row >> 1) & 3)) << 3;
    gload_lds16(Abase + (size_t)row * K + kk + col, &lA[j & 1][wave * 512]);
  };
  auto stB = [&](int j) {            // 16 KB: 2 issues/thread
    int kk = j << 5;
    #pragma unroll
    for (int c = 0; c < 2; ++c) {
      int chunk = c * 512 + tid;
      int row = chunk >> 2;
      int col = ((chunk & 3) ^ ((row >> 1) & 3)) << 3;
      gload_lds16(Bbase + (size_t)row * K + kk + col,
                  &lB[j & 1][c * 4096 + wave * 512]);
    }
  };

  f32x4 acc[4][4];
  const f32x4 z4 = {0.f, 0.f, 0.f, 0.f};
  #pragma unroll
  for (int i = 0; i < 4; ++i)
    #pragma unroll
    for (int j = 0; j < 4; ++j) acc[i][j] = z4;

  const int sw8 = ((g ^ ((r >> 1) & 3)) << 3);
  const int laneA = (wr * 64 + r) * 32 + sw8;
  const int laneB = (wc * 64 + r) * 32 + sw8;

  stA(0); stB(0);
  asm volatile("s_waitcnt vmcnt(0)" ::: "memory");
  __builtin_amdgcn_s_barrier();

  for (int j = 0; j < nk; ++j) {
    if (j + 1 < nk) { stA(j + 1); stB(j + 1); }   // writes slot (j+1)&1
    const u16* bA = &lA[j & 1][0];
    const u16* bB = &lB[j & 1][0];
    bf16x8 af[4], bf[4];
    #pragma unroll
    for (int mi = 0; mi < 4; ++mi)
      af[mi] = *(const bf16x8*)&bA[laneA + mi * 512];
    #pragma unroll
    for (int ni = 0; ni < 4; ++ni)
      bf[ni] = *(const bf16x8*)&bB[laneB + ni * 512];
    __builtin_amdgcn_s_setprio(1);
    #pragma unroll
    for (int mi = 0; mi < 4; ++mi)
      #pragma unroll
      for (int ni = 0; ni < 4; ++ni)
        acc[mi][ni] = mfma16(af[mi], bf[ni], acc[mi][ni]);
    __builtin_amdgcn_s_setprio(0);
    asm volatile("s_waitcnt vmcnt(0)" ::: "memory");  // drain prefetch j+1
    __builtin_amdgcn_s_barrier();                     // all reads of slot done
  }

  #pragma unroll
  for (int mi = 0; mi < 4; ++mi)
    #pragma unroll
    for (int ni = 0; ni < 4; ++ni)
      #pragma unroll
      for (int rr = 0; rr < 4; ++rr) {
        int row = mtile * 128 + wr * 64 + mi * 16 + g * 4 + rr;
        int col = ntile * 256 + wc * 64 + ni * 16 + r;
        C[(size_t)row * N + col] = f2bf(acc[mi][ni][rr]);
      }
}

// ---------------- GEMM 128x128 (O-projection), XCD-chunked flat grid ------
template<int F32OUT>
__global__ __launch_bounds__(256, 3)
void gemm128(const u16* __restrict__ A, const u16* __restrict__ Bt,
             void* __restrict__ C, int M, int N, int K) {
  const int tid = threadIdx.x;
  const int wave = tid >> 6, lane = tid & 63;
  const int bid = blockIdx.x;
  const int wg = (bid & 7) * (gridDim.x >> 3) + (bid >> 3);  // XCD-chunked
  const int mt = wg & 31, nt0 = wg >> 5;
  __shared__ __align__(16) u16 ldsA[2][128 * 32];
  __shared__ __align__(16) u16 ldsB[2][128 * 32];

  const int wm = (wave >> 1) * 64, wn = (wave & 1) * 64;
  const int r = lane & 15, g = lane >> 4;

  f32x4 acc[4][4];
  const f32x4 z4 = {0.f, 0.f, 0.f, 0.f};
  #pragma unroll
  for (int i = 0; i < 4; ++i)
    #pragma unroll
    for (int j = 0; j < 4; ++j) acc[i][j] = z4;

  const u16* Abase = A + (size_t)mt * 128 * K;
  const u16* Bbase = Bt + (size_t)nt0 * 128 * K;

  auto stage = [&](u16* dst, const u16* src, int kb) {
    #pragma unroll
    for (int c = 0; c < 2; ++c) {
      int chunk = wave * 128 + c * 64 + lane;
      int row = chunk >> 2;
      int colb = (chunk & 3) << 4;
      int scolb = colb ^ (((row >> 1) & 3) << 4);
      gload_lds16(src + (size_t)row * K + kb + (scolb >> 1),
                  dst + (wave * 128 + c * 64) * 8);
    }
  };

  const int nk = K >> 5;
  stage(ldsA[0], Abase, 0);
  stage(ldsB[0], Bbase, 0);
  __syncthreads();

  for (int kt = 0; kt < nk; ++kt) {
    const int cur = kt & 1;
    if (kt + 1 < nk) {
      stage(ldsA[cur ^ 1], Abase, (kt + 1) << 5);
      stage(ldsB[cur ^ 1], Bbase, (kt + 1) << 5);
    }
    bf16x8 af[4], bfr[4];
    #pragma unroll
    for (int mi = 0; mi < 4; ++mi) {
      int row = wm + mi * 16 + r;
      int off = row * 32 + (((g << 4) ^ (((row >> 1) & 3) << 4)) >> 1);
      af[mi] = *(const bf16x8*)&ldsA[cur][off];
    }
    #pragma unroll
    for (int ni = 0; ni < 4; ++ni) {
      int row = wn + ni * 16 + r;
      int off = row * 32 + (((g << 4) ^ (((row >> 1) & 3) << 4)) >> 1);
      bfr[ni] = *(const bf16x8*)&ldsB[cur][off];
    }
    __builtin_amdgcn_s_setprio(1);
    #pragma unroll
    for (int mi = 0; mi < 4; ++mi)
      #pragma unroll
      for (int ni = 0; ni < 4; ++ni)
        acc[mi][ni] = mfma16(af[mi], bfr[ni], acc[mi][ni]);
    __builtin_amdgcn_s_setprio(0);
    __syncthreads();
  }

  #pragma unroll
  for (int mi = 0; mi < 4; ++mi)
    #pragma unroll
    for (int ni = 0; ni < 4; ++ni)
      #pragma unroll
      for (int rr = 0; rr < 4; ++rr) {
        int row = mt * 128 + wm + mi * 16 + g * 4 + rr;
        int col = nt0 * 128 + wn + ni * 16 + r;
        float v = acc[mi][ni][rr];
        if (F32OUT) ((float*)C)[(size_t)row * N + col] = v;
        else        ((u16*)C)[(size_t)row * N + col] = f2bf(v);
      }
}

// ---------------- RoPE + rearrange (vectorized 8/thread) ------------------
__global__ __launch_bounds__(256)
void rope_rearrange(const u16* __restrict__ src, int ldsrc,
                    const u16* __restrict__ cosT, const u16* __restrict__ sinT,
                    u16* __restrict__ dst, float scale) {
  int id = blockIdx.x * 256 + threadIdx.x;
  int c8 = id & 7;               // 8-elem chunk within [0,64)
  int hh = (id >> 3) & 15;
  int tok = id >> 7;             // 0..32767
  int n = tok & (SEQ - 1);
  int b = tok >> 11;
  const u16* s = src + (size_t)tok * ldsrc + hh * DH + c8 * 8;
  uint4 d1 = *(const uint4*)s;
  uint4 d2 = *(const uint4*)(s + 64);
  const u16* ct = cosT + n * DH + c8 * 8;
  const u16* st = sinT + n * DH + c8 * 8;
  uint4 c1 = *(const uint4*)ct, c2 = *(const uint4*)(ct + 64);
  uint4 s1 = *(const uint4*)st, s2 = *(const uint4*)(st + 64);
  const u16* d1p = (const u16*)&d1; const u16* d2p = (const u16*)&d2;
  const u16* c1p = (const u16*)&c1; const u16* c2p = (const u16*)&c2;
  const u16* s1p = (const u16*)&s1; const u16* s2p = (const u16*)&s2;
  u16 o1[8], o2[8];
  #pragma unroll
  for (int i = 0; i < 8; ++i) {
    float t1 = bf2f(d1p[i]), t2 = bf2f(d2p[i]);
    o1[i] = f2bf((t1 * bf2f(c1p[i]) - t2 * bf2f(s1p[i])) * scale);
    o2[i] = f2bf((t2 * bf2f(c2p[i]) + t1 * bf2f(s2p[i])) * scale);
  }
  u16* dp = dst + ((size_t)(b * HEADS + hh) * SEQ + n) * DH + c8 * 8;
  *(uint4*)dp = *(const uint4*)o1;
  *(uint4*)(dp + 64) = *(const uint4*)o2;
}

// ---------------- V transpose: v0[NTOK][ld] -> vT[B][H][DH][SEQ] ----------
__global__ __launch_bounds__(256)
void transp_v(const u16* __restrict__ v0, int ld, u16* __restrict__ vTo) {
  __shared__ __align__(16) u16 t[32][136];
  const int id = blockIdx.x;
  const int ntile = id & 63;
  const int hh = (id >> 6) & 15;
  const int b = id >> 10;
  const int tid = threadIdx.x;
  const int n0 = ntile * 32;
  #pragma unroll
  for (int it = 0; it < 2; ++it) {
    int chunk = it * 256 + tid;
    int nr = chunk >> 4, dc = chunk & 15;
    const u16* src = v0 + (size_t)(b * SEQ + n0 + nr) * ld + hh * DH + dc * 8;
    *(uint4*)&t[nr][dc * 8] = *(const uint4*)src;
  }
  __syncthreads();
  int d = tid >> 1, nh = tid & 1;
  u16 tmp[16];
  #pragma unroll
  for (int j = 0; j < 16; ++j) tmp[j] = t[nh * 16 + j][d];
  u16* dst = vTo + ((size_t)(b * HEADS + hh) * DH + d) * SEQ + n0 + nh * 16;
  *(uint4*)&dst[0] = *(const uint4*)&tmp[0];
  *(uint4*)&dst[8] = *(const uint4*)&tmp[8];
}

// ---------------- flash attention (causal) --------------------------------
// R12-best config: 4-wave blocks (grid 512 -> 2 blocks/CU, independent
// barrier domains), swapped-QK^T in-register softmax, T1 XCD swizzle
// (4 heads' K/V per XCD L2), 2-slot ring, 72 KB LDS.
__global__ __launch_bounds__(256)
void flash(const u16* __restrict__ qr, const u16* __restrict__ kr,
           const u16* __restrict__ vT, u16* __restrict__ attn) {
  const int bid = blockIdx.x;
  const int swz = (bid & 7) * 64 + (bid >> 3);   // T1 remap, 512%8==0
  const int hb = swz >> 4, pairi = swz & 15;     // hb 0..31: 4 heads/XCD
  const int h = hb & 15, b = hb >> 4;
  const int tid = threadIdx.x, wave = tid >> 6, lane = tid & 63;
  const int r = lane & 15, g = lane >> 4;

  __shared__ __align__(16) u16 kT[2][64 * 128];
  __shared__ __align__(16) u16 vS[2][128 * 64];
  __shared__ __align__(16) u16 pS[4][16 * 64];

  const size_t headq = (size_t)(b * HEADS + h) * SEQ;
  const u16* kbase = kr + headq * DH;
  const u16* vbase = vT + (size_t)(b * HEADS + h) * DH * SEQ;

  auto stageKV = [&](int buf, int kt) {        // 8 issues/thread (K:4, V:4)
    #pragma unroll
    for (int c = 0; c < 4; ++c) {
      int chunk = (wave * 4 + c) * 64 + lane;          // 0..1023
      int row = chunk >> 4;
      int scolb = ((chunk & 15) << 4) ^ ((row & 7) << 4);
      gload_lds16(kbase + (size_t)(kt * 64 + row) * DH + (scolb >> 1),
                  kT[buf] + (wave * 4 + c) * 64 * 8);
    }
    #pragma unroll
    for (int c = 0; c < 4; ++c) {
      int chunk = (wave * 4 + c) * 64 + lane;
      int d = chunk >> 3;
      int sb = ((chunk & 7) << 4) ^ ((d & 7) << 4);
      gload_lds16(vbase + (size_t)d * SEQ + kt * 64 + (sb >> 1),
                  vS[buf] + (wave * 4 + c) * 64 * 8);
    }
  };

  const f32x4 z4 = {0.f, 0.f, 0.f, 0.f};

  #pragma unroll 1
  for (int pass = 0; pass < 2; ++pass) {
    const int qt = pass ? (31 - pairi) : pairi;
    const int nkv = qt + 1;

    const u16* qbase = qr + (headq + qt * 64 + wave * 16) * DH;
    bf16x8 qf[4];
    #pragma unroll
    for (int ks = 0; ks < 4; ++ks)
      qf[ks] = *(const bf16x8*)(qbase + r * DH + ks * 32 + g * 8);

    f32x4 o[8];
    #pragma unroll
    for (int i = 0; i < 8; ++i) o[i] = z4;
    float m = -3.0e38f, lsum = 0.f;        // per-lane scalars (q = r)

    stageKV(0, 0);
    __syncthreads();

    for (int kt = 0; kt < nkv; ++kt) {
      const int cur = kt & 1;
      if (kt + 1 < nkv) stageKV(cur ^ 1, kt + 1);

      // S^T: lane(r,g), reg rr: k = nt*16 + g*4 + rr, q = r
      f32x4 s[4];
      #pragma unroll
      for (int i = 0; i < 4; ++i) s[i] = z4;
      __builtin_amdgcn_s_setprio(1);
      #pragma unroll
      for (int ks = 0; ks < 4; ++ks) {
        #pragma unroll
        for (int nt = 0; nt < 4; ++nt) {
          int krow = nt * 16 + r;
          int koff = krow * 128 + (((ks * 64 + g * 16) ^ ((krow & 7) << 4)) >> 1);
          bf16x8 kf = *(const bf16x8*)&kT[cur][koff];
          s[nt] = mfma16(kf, qf[ks], s[nt]);   // SWAPPED operands
        }
      }
      __builtin_amdgcn_s_setprio(0);

      if (kt == qt) {                    // diagonal causal mask: k > q
        #pragma unroll
        for (int nt = 0; nt < 4; ++nt)
          #pragma unroll
          for (int rr = 0; rr < 4; ++rr) {
            int kloc = nt * 16 + g * 4 + rr;
            int qloc = wave * 16 + r;
            if (kloc > qloc) s[nt][rr] = -1e30f;
          }
      }

      float mx = s[0][0];
      #pragma unroll
      for (int nt = 0; nt < 4; ++nt)
        #pragma unroll
        for (int rr = 0; rr < 4; ++rr)
          mx = fmaxf(mx, s[nt][rr]);
      mx = fmaxf(mx, __shfl_xor(mx, 16));
      mx = fmaxf(mx, __shfl_xor(mx, 32));
      float mnew = fmaxf(m, mx);
      float alpha = exp2f(m - mnew);
      m = mnew;

      float rs = 0.f;
      float p[4][4];
      #pragma unroll
      for (int nt = 0; nt < 4; ++nt)
        #pragma unroll
        for (int rr = 0; rr < 4; ++rr) {
          p[nt][rr] = exp2f(s[nt][rr] - mnew);
          rs += p[nt][rr];
        }
      rs += __shfl_xor(rs, 16);
      rs += __shfl_xor(rs, 32);
      lsum = lsum * alpha + rs;
      #pragma unroll
      for (int dt = 0; dt < 8; ++dt)
        o[dt] *= alpha;

      // pack P -> LDS: 4x b64 per lane at [q=r][k = nt*16+g*4 .. +3]
      #pragma unroll
      for (int nt = 0; nt < 4; ++nt) {
        bf16x4 pk;
        pk[0] = (short)f2bf(p[nt][0]); pk[1] = (short)f2bf(p[nt][1]);
        pk[2] = (short)f2bf(p[nt][2]); pk[3] = (short)f2bf(p[nt][3]);
        int elem = r * 64 + ((nt * 16 + g * 4) ^ ((r & 7) << 3));
        *(bf16x4*)&pS[wave][elem] = pk;
      }

      // O^T += V(A) x P(B): lane(r,g) rr: d = dt*16+g*4+rr, q = r
      __builtin_amdgcn_s_setprio(1);
      #pragma unroll
      for (int ks = 0; ks < 2; ++ks) {
        int pfe = r * 64 + ((ks * 32 + g * 8) ^ ((r & 7) << 3));
        bf16x8 pf = *(const bf16x8*)&pS[wave][pfe];
        #pragma unroll
        for (int dt = 0; dt < 8; ++dt) {
          int vrow = dt * 16 + r;
          int voff = vrow * 64 + (((ks * 64 + g * 16) ^ ((vrow & 7) << 4)) >> 1);
          bf16x8 vf = *(const bf16x8*)&vS[cur][voff];
          o[dt] = mfma16(vf, pf, o[dt]);   // SWAPPED: V as A, P as B
        }
      }
      __builtin_amdgcn_s_setprio(0);

      __syncthreads();   // drains prefetch; guards buffer reuse
    }

    // epilogue: O^T -> LDS transpose (per-wave, reuses pS) -> coalesced store
    float inv = 1.0f / lsum;
    #pragma unroll
    for (int dh = 0; dh < 2; ++dh) {
      #pragma unroll
      for (int dt4 = 0; dt4 < 4; ++dt4) {
        int dt = dh * 4 + dt4;
        bf16x4 ovp;
        ovp[0] = (short)f2bf(o[dt][0] * inv);
        ovp[1] = (short)f2bf(o[dt][1] * inv);
        ovp[2] = (short)f2bf(o[dt][2] * inv);
        ovp[3] = (short)f2bf(o[dt][3] * inv);
        int elem = r * 64 + (((dt4 * 16 + g * 4)) ^ ((r & 7) << 3));
        *(bf16x4*)&pS[wave][elem] = ovp;
      }
      #pragma unroll
      for (int i = 0; i < 2; ++i) {
        int c = i * 64 + lane;
        int qq = c >> 3, dc = c & 7;
        int elem = qq * 64 + ((dc * 8) ^ ((qq & 7) << 3));
        uint4 val = *(const uint4*)&pS[wave][elem];
        *(uint4*)&attn[((size_t)b * SEQ + qt * 64 + wave * 16 + qq) * INNER +
                       h * DH + dh * 64 + dc * 8] = val;
      }
    }
    __syncthreads();
  }
}

// ---------------- host ----------------
extern "C" void kernel_launch(void* const* d_in, const int* in_sizes, int n_in,
                              void* d_out, int out_size, void* d_ws, size_t ws_size,
                              hipStream_t stream) {
  const float* x   = (const float*)d_in[0];
  const float* rot = (const float*)d_in[1];
  const float* g   = (const float*)d_in[2];
  const float* Wq  = (const float*)d_in[3];
  const float* Wkv = (const float*)d_in[4];
  const float* Wo  = (const float*)d_in[5];

  char* ws = (char*)d_ws;
  size_t off = 0;
  auto alloc = [&](size_t bytes) {
    char* p = ws + off;
    off += (bytes + 255) & ~(size_t)255;
    return p;
  };
  u16*   WqkvT = (u16*)alloc((size_t)6144 * 2048 * 2);  // q rows 0-2047, k 2048-4095, v 4096-6143
  u16*   WoT   = (u16*)alloc((size_t)2048 * 2048 * 2);
  u16*   cosT  = (u16*)alloc((size_t)2048 * 128 * 2);
  u16*   sinT  = (u16*)alloc((size_t)2048 * 128 * 2);
  u16*   xn    = (u16*)alloc((size_t)4096 * 2048 * 2);
  u16*   qkv   = (u16*)alloc((size_t)4096 * 6144 * 2);
  u16*   qr    = (u16*)alloc((size_t)4096 * 2048 * 2);
  // region reuse (dependency-checked against launch order below):
  u16* kr   = WqkvT;  // WqkvT (25.2MB >= 16.8MB) dead after QKV GEMM
  u16* vt   = xn;     // xn dead after QKV GEMM
  u16* attn = qkv;    // qkv dead after rope_q + rope_k + transp_v

  // rope-q scale = 1/sqrt(128) * log2(e)  (softmax runs in exp2 domain)
  const float qscale = 0.08838834764831845f * 1.4426950408889634f;

  transpose_cast<<<dim3(1024), 256, 0, stream>>>(Wq,  WqkvT,               2048, 2048);
  transpose_cast<<<dim3(2048), 256, 0, stream>>>(Wkv, WqkvT + 2048 * 2048, 2048, 4096);
  transpose_cast<<<dim3(1024), 256, 0, stream>>>(Wo,  WoT,                 2048, 2048);
  build_tables<<<dim3(2048 * 128 / 256), 256, 0, stream>>>(rot, cosT, sinT);
  rmsnorm_k<<<dim3(4096), 256, 0, stream>>>(x, g, xn);
  gemm_qkv<<<dim3(768), 512, 0, stream>>>(xn, WqkvT, qkv, 4096, 6144, 2048);
  rope_rearrange<<<dim3(2048), 256, 0, stream>>>(qkv,        6144, cosT, sinT, qr, qscale);
  rope_rearrange<<<dim3(2048), 256, 0, stream>>>(qkv + 2048, 6144, cosT, sinT, kr, 1.0f);
  transp_v<<<dim3(2048), 256, 0, stream>>>(qkv + 4096, 6144, vt);
  flash<<<dim3(512), 256, 0, stream>>>(qr, kr, vt, attn);
  gemm128<1><<<dim3(512), 256, 0, stream>>>(attn, WoT, (float*)d_out, 4096, 2048, 2048);
}

// Round 16
// 286.486 us; speedup vs baseline: 1.0834x; 1.0158x over previous
//
#include <hip/hip_runtime.h>
#include <cstdint>
#include <cstddef>

#define DIM    2048
#define HEADS  16
#define DH     128
#define INNER  2048
#define SEQ    2048
#define BATCH  2
#define NTOK   4096

typedef unsigned short u16;
typedef __attribute__((ext_vector_type(4))) short bf16x4;
typedef __attribute__((ext_vector_type(8))) short bf16x8;
typedef __attribute__((ext_vector_type(4))) float f32x4;

__device__ __forceinline__ u16 f2bf(float f) {
  union { float f; unsigned u; } v; v.f = f;
  unsigned r = v.u + 0x7FFFu + ((v.u >> 16) & 1u);
  return (u16)(r >> 16);
}
__device__ __forceinline__ float bf2f(u16 h) {
  union { unsigned u; float f; } v; v.u = ((unsigned)h) << 16;
  return v.f;
}

using as1_t = __attribute__((address_space(1))) const void;
using as3_t = __attribute__((address_space(3))) void;
__device__ __forceinline__ void gload_lds16(const void* g, void* l) {
  __builtin_amdgcn_global_load_lds((as1_t*)g, (as3_t*)l, 16, 0, 0);
}

__device__ __forceinline__ f32x4 mfma16(bf16x8 a, bf16x8 b, f32x4 c) {
  return __builtin_amdgcn_mfma_f32_16x16x32_bf16(a, b, c, 0, 0, 0);
}

// ---------------- weight transpose + cast, vectorized: W[K][N] -> Wt[N][K] -
__global__ __launch_bounds__(256)
void transpose_cast(const float* __restrict__ W, u16* __restrict__ Wt,
                    int K, int N) {
  __shared__ float t[64][65];
  const int tiles_n = N >> 6;
  const int tx = blockIdx.x % tiles_n, ty = blockIdx.x / tiles_n;
  const int tid = threadIdx.x;
  const int k0 = ty << 6, n0 = tx << 6;
  #pragma unroll
  for (int i = 0; i < 4; ++i) {       // 64 k-rows x 16 float4
    int e = tid + i * 256;
    int kr = e >> 4, c4 = e & 15;
    *(float4*)&t[kr][c4 * 4] =
        *(const float4*)&W[(size_t)(k0 + kr) * N + n0 + c4 * 4];
  }
  __syncthreads();
  #pragma unroll
  for (int i = 0; i < 2; ++i) {       // 64 n-rows x 8 k8-chunks
    int e = tid + i * 256;
    int nr = e >> 3, k8 = e & 7;
    u16 o[8];
    #pragma unroll
    for (int j = 0; j < 8; ++j) o[j] = f2bf(t[k8 * 8 + j][nr]);
    *(uint4*)&Wt[(size_t)(n0 + nr) * K + k0 + k8 * 8] = *(const uint4*)o;
  }
}

// ---------------- rope cos/sin tables (bf16) ----------------
__global__ __launch_bounds__(256)
void build_tables(const float* __restrict__ rot, u16* __restrict__ cosT,
                  u16* __restrict__ sinT) {
  int i = blockIdx.x * 256 + threadIdx.x;
  float v = rot[i];
  cosT[i] = f2bf(cosf(v));
  sinT[i] = f2bf(sinf(v));
}

// ---------------- RMSNorm: x f32 [NTOK][DIM] -> xn bf16 ----------------
__global__ __launch_bounds__(256)
void rmsnorm_k(const float* __restrict__ x, const float* __restrict__ gw,
               u16* __restrict__ xn) {
  const int row = blockIdx.x, tid = threadIdx.x;
  const float4* x4 = (const float4*)(x + (size_t)row * DIM);
  float4 a = x4[tid * 2], b = x4[tid * 2 + 1];
  float ss = a.x*a.x + a.y*a.y + a.z*a.z + a.w*a.w
           + b.x*b.x + b.y*b.y + b.z*b.z + b.w*b.w;
  #pragma unroll
  for (int off = 1; off < 64; off <<= 1) ss += __shfl_xor(ss, off);
  __shared__ float red[4];
  if ((tid & 63) == 0) red[tid >> 6] = ss;
  __syncthreads();
  float tot = red[0] + red[1] + red[2] + red[3];
  float sc = 1.0f / fmaxf(sqrtf(tot * (1.0f / DIM)), 1e-8f);
  const float4* g4 = (const float4*)gw;
  float4 ga = g4[tid * 2], gb = g4[tid * 2 + 1];
  u16 ov[8];
  ov[0] = f2bf(a.x * sc * ga.x); ov[1] = f2bf(a.y * sc * ga.y);
  ov[2] = f2bf(a.z * sc * ga.z); ov[3] = f2bf(a.w * sc * ga.w);
  ov[4] = f2bf(b.x * sc * gb.x); ov[5] = f2bf(b.y * sc * gb.y);
  ov[6] = f2bf(b.z * sc * gb.z); ov[7] = f2bf(b.w * sc * gb.w);
  *(uint4*)(xn + (size_t)row * DIM + tid * 8) = *(const uint4*)ov;
}

// ---------------- fused QKV GEMM: 128x256, 2-slot dbuf, 2 blocks/CU -------
// (R8 config, banked best: ~130us / MfmaUtil 34.5 / 0 conflicts. PARKED.)
__global__ __launch_bounds__(512, 4)
void gemm_qkv(const u16* __restrict__ A, const u16* __restrict__ Bt,
              u16* __restrict__ C, int M, int N, int K) {
  __shared__ __align__(16) u16 lA[2][128 * 32];
  __shared__ __align__(16) u16 lB[2][256 * 32];
  const int tid = threadIdx.x;
  const int wave = tid >> 6, lane = tid & 63;
  const int r = lane & 15, g = lane >> 4;
  const int wr = wave >> 2, wc = wave & 3;   // 2M x 4N wave grid

  const int bid = blockIdx.x;
  const int wg = (bid & 7) * 96 + (bid >> 3);   // XCD-chunked, 768%8==0
  const int mtile = wg & 31;                    // inner: A panel streams
  const int ntile = wg >> 5;                    // 0..23: B panel L2-resident

  const u16* Abase = A + (size_t)mtile * 128 * K;
  const u16* Bbase = Bt + (size_t)ntile * 256 * K;
  const int nk = K >> 5;   // 64 K-tiles

  auto stA = [&](int j) {            // 8 KB: 1 issue/thread
    int kk = j << 5;
    int row = tid >> 2;
    int col = ((tid & 3) ^ ((row >> 1) & 3)) << 3;
    gload_lds16(Abase + (size_t)row * K + kk + col, &lA[j & 1][wave * 512]);
  };
  auto stB = [&](int j) {            // 16 KB: 2 issues/thread
    int kk = j << 5;
    #pragma unroll
    for (int c = 0; c < 2; ++c) {
      int chunk = c * 512 + tid;
      int row = chunk >> 2;
      int col = ((chunk & 3) ^ ((row >> 1) & 3)) << 3;
      gload_lds16(Bbase + (size_t)row * K + kk + col,
                  &lB[j & 1][c * 4096 + wave * 512]);
    }
  };

  f32x4 acc[4][4];
  const f32x4 z4 = {0.f, 0.f, 0.f, 0.f};
  #pragma unroll
  for (int i = 0; i < 4; ++i)
    #pragma unroll
    for (int j = 0; j < 4; ++j) acc[i][j] = z4;

  const int sw8 = ((g ^ ((r >> 1) & 3)) << 3);
  const int laneA = (wr * 64 + r) * 32 + sw8;
  const int laneB = (wc * 64 + r) * 32 + sw8;

  stA(0); stB(0);
  asm volatile("s_waitcnt vmcnt(0)" ::: "memory");
  __builtin_amdgcn_s_barrier();

  for (int j = 0; j < nk; ++j) {
    if (j + 1 < nk) { stA(j + 1); stB(j + 1); }   // writes slot (j+1)&1
    const u16* bA = &lA[j & 1][0];
    const u16* bB = &lB[j & 1][0];
    bf16x8 af[4], bf[4];
    #pragma unroll
    for (int mi = 0; mi < 4; ++mi)
      af[mi] = *(const bf16x8*)&bA[laneA + mi * 512];
    #pragma unroll
    for (int ni = 0; ni < 4; ++ni)
      bf[ni] = *(const bf16x8*)&bB[laneB + ni * 512];
    __builtin_amdgcn_s_setprio(1);
    #pragma unroll
    for (int mi = 0; mi < 4; ++mi)
      #pragma unroll
      for (int ni = 0; ni < 4; ++ni)
        acc[mi][ni] = mfma16(af[mi], bf[ni], acc[mi][ni]);
    __builtin_amdgcn_s_setprio(0);
    asm volatile("s_waitcnt vmcnt(0)" ::: "memory");  // drain prefetch j+1
    __builtin_amdgcn_s_barrier();                     // all reads of slot done
  }

  #pragma unroll
  for (int mi = 0; mi < 4; ++mi)
    #pragma unroll
    for (int ni = 0; ni < 4; ++ni)
      #pragma unroll
      for (int rr = 0; rr < 4; ++rr) {
        int row = mtile * 128 + wr * 64 + mi * 16 + g * 4 + rr;
        int col = ntile * 256 + wc * 64 + ni * 16 + r;
        C[(size_t)row * N + col] = f2bf(acc[mi][ni][rr]);
      }
}

// ---------------- GEMM 128x128 (O-projection), XCD-chunked flat grid ------
template<int F32OUT>
__global__ __launch_bounds__(256, 3)
void gemm128(const u16* __restrict__ A, const u16* __restrict__ Bt,
             void* __restrict__ C, int M, int N, int K) {
  const int tid = threadIdx.x;
  const int wave = tid >> 6, lane = tid & 63;
  const int bid = blockIdx.x;
  const int wg = (bid & 7) * (gridDim.x >> 3) + (bid >> 3);  // XCD-chunked
  const int mt = wg & 31, nt0 = wg >> 5;
  __shared__ __align__(16) u16 ldsA[2][128 * 32];
  __shared__ __align__(16) u16 ldsB[2][128 * 32];

  const int wm = (wave >> 1) * 64, wn = (wave & 1) * 64;
  const int r = lane & 15, g = lane >> 4;

  f32x4 acc[4][4];
  const f32x4 z4 = {0.f, 0.f, 0.f, 0.f};
  #pragma unroll
  for (int i = 0; i < 4; ++i)
    #pragma unroll
    for (int j = 0; j < 4; ++j) acc[i][j] = z4;

  const u16* Abase = A + (size_t)mt * 128 * K;
  const u16* Bbase = Bt + (size_t)nt0 * 128 * K;

  auto stage = [&](u16* dst, const u16* src, int kb) {
    #pragma unroll
    for (int c = 0; c < 2; ++c) {
      int chunk = wave * 128 + c * 64 + lane;
      int row = chunk >> 2;
      int colb = (chunk & 3) << 4;
      int scolb = colb ^ (((row >> 1) & 3) << 4);
      gload_lds16(src + (size_t)row * K + kb + (scolb >> 1),
                  dst + (wave * 128 + c * 64) * 8);
    }
  };

  const int nk = K >> 5;
  stage(ldsA[0], Abase, 0);
  stage(ldsB[0], Bbase, 0);
  __syncthreads();

  for (int kt = 0; kt < nk; ++kt) {
    const int cur = kt & 1;
    if (kt + 1 < nk) {
      stage(ldsA[cur ^ 1], Abase, (kt + 1) << 5);
      stage(ldsB[cur ^ 1], Bbase, (kt + 1) << 5);
    }
    bf16x8 af[4], bfr[4];
    #pragma unroll
    for (int mi = 0; mi < 4; ++mi) {
      int row = wm + mi * 16 + r;
      int off = row * 32 + (((g << 4) ^ (((row >> 1) & 3) << 4)) >> 1);
      af[mi] = *(const bf16x8*)&ldsA[cur][off];
    }
    #pragma unroll
    for (int ni = 0; ni < 4; ++ni) {
      int row = wn + ni * 16 + r;
      int off = row * 32 + (((g << 4) ^ (((row >> 1) & 3) << 4)) >> 1);
      bfr[ni] = *(const bf16x8*)&ldsB[cur][off];
    }
    __builtin_amdgcn_s_setprio(1);
    #pragma unroll
    for (int mi = 0; mi < 4; ++mi)
      #pragma unroll
      for (int ni = 0; ni < 4; ++ni)
        acc[mi][ni] = mfma16(af[mi], bfr[ni], acc[mi][ni]);
    __builtin_amdgcn_s_setprio(0);
    __syncthreads();
  }

  #pragma unroll
  for (int mi = 0; mi < 4; ++mi)
    #pragma unroll
    for (int ni = 0; ni < 4; ++ni)
      #pragma unroll
      for (int rr = 0; rr < 4; ++rr) {
        int row = mt * 128 + wm + mi * 16 + g * 4 + rr;
        int col = nt0 * 128 + wn + ni * 16 + r;
        float v = acc[mi][ni][rr];
        if (F32OUT) ((float*)C)[(size_t)row * N + col] = v;
        else        ((u16*)C)[(size_t)row * N + col] = f2bf(v);
      }
}

// ---------------- FUSED rope(q,k) + V transpose -----------------------------
// One block = 32 tokens x 1 head (grid 2048). Replaces rope_q, rope_k and
// transp_v: reads each token's cos/sin ONCE for both q and k, saves two
// kernel launches and the duplicated address math. Numerics identical.
// Rope part: thread = (row 0..31, pair-chunk 0..7); q uses qscale (exp2
// domain), k uses 1.0. V part: transp_v's LDS [32][136] tile unchanged.
__global__ __launch_bounds__(256)
void rope_fused(const u16* __restrict__ qkv,
                const u16* __restrict__ cosT, const u16* __restrict__ sinT,
                u16* __restrict__ qr, u16* __restrict__ kr,
                u16* __restrict__ vt, float qscale) {
  const int id = blockIdx.x;
  const int ntile = id & 63;
  const int hh = (id >> 6) & 15;
  const int b = id >> 10;
  const int tid = threadIdx.x;
  const int n0 = ntile * 32;
  __shared__ __align__(16) u16 t[32][136];

  // ---- rope q + k (1 row-pair-chunk per thread) ----
  {
    const int row = tid >> 3;          // 0..31
    const int dcp = tid & 7;           // d = dcp*8 .. +7, partner +64
    const int n = n0 + row;
    const u16* ct = cosT + n * DH + dcp * 8;
    const u16* st = sinT + n * DH + dcp * 8;
    uint4 c1 = *(const uint4*)ct, c2 = *(const uint4*)(ct + 64);
    uint4 s1 = *(const uint4*)st, s2 = *(const uint4*)(st + 64);
    const u16* c1p = (const u16*)&c1; const u16* c2p = (const u16*)&c2;
    const u16* s1p = (const u16*)&s1; const u16* s2p = (const u16*)&s2;
    const size_t tokbase = (size_t)(b * SEQ + n) * 6144 + hh * DH + dcp * 8;
    u16* qdst = qr + ((size_t)(b * HEADS + hh) * SEQ + n) * DH + dcp * 8;
    u16* kdst = kr + ((size_t)(b * HEADS + hh) * SEQ + n) * DH + dcp * 8;
    #pragma unroll
    for (int which = 0; which < 2; ++which) {   // 0 = q, 1 = k
      const u16* src = qkv + tokbase + which * 2048;
      const float sc = which ? 1.0f : qscale;
      uint4 d1 = *(const uint4*)src, d2 = *(const uint4*)(src + 64);
      const u16* d1p = (const u16*)&d1; const u16* d2p = (const u16*)&d2;
      u16 o1[8], o2[8];
      #pragma unroll
      for (int i = 0; i < 8; ++i) {
        float t1 = bf2f(d1p[i]), t2 = bf2f(d2p[i]);
        o1[i] = f2bf((t1 * bf2f(c1p[i]) - t2 * bf2f(s1p[i])) * sc);
        o2[i] = f2bf((t2 * bf2f(c2p[i]) + t1 * bf2f(s2p[i])) * sc);
      }
      u16* dst = which ? kdst : qdst;
      *(uint4*)dst = *(const uint4*)o1;
      *(uint4*)(dst + 64) = *(const uint4*)o2;
    }
  }

  // ---- V transpose (transp_v body, v at qkv column offset 4096) ----
  #pragma unroll
  for (int it = 0; it < 2; ++it) {
    int chunk = it * 256 + tid;
    int nr = chunk >> 4, dc = chunk & 15;
    const u16* src = qkv + (size_t)(b * SEQ + n0 + nr) * 6144 + 4096 +
                     hh * DH + dc * 8;
    *(uint4*)&t[nr][dc * 8] = *(const uint4*)src;
  }
  __syncthreads();
  int d = tid >> 1, nh = tid & 1;
  u16 tmp[16];
  #pragma unroll
  for (int j = 0; j < 16; ++j) tmp[j] = t[nh * 16 + j][d];
  u16* dst = vt + ((size_t)(b * HEADS + hh) * DH + d) * SEQ + n0 + nh * 16;
  *(uint4*)&dst[0] = *(const uint4*)&tmp[0];
  *(uint4*)&dst[8] = *(const uint4*)&tmp[8];
}

// ---------------- flash attention (causal) --------------------------------
// R12-best config: 4-wave blocks (grid 512 -> 2 blocks/CU, independent
// barrier domains), swapped-QK^T in-register softmax, T1 XCD swizzle
// (4 heads' K/V per XCD L2), 2-slot ring, 72 KB LDS.
__global__ __launch_bounds__(256)
void flash(const u16* __restrict__ qr, const u16* __restrict__ kr,
           const u16* __restrict__ vT, u16* __restrict__ attn) {
  const int bid = blockIdx.x;
  const int swz = (bid & 7) * 64 + (bid >> 3);   // T1 remap, 512%8==0
  const int hb = swz >> 4, pairi = swz & 15;     // hb 0..31: 4 heads/XCD
  const int h = hb & 15, b = hb >> 4;
  const int tid = threadIdx.x, wave = tid >> 6, lane = tid & 63;
  const int r = lane & 15, g = lane >> 4;

  __shared__ __align__(16) u16 kT[2][64 * 128];
  __shared__ __align__(16) u16 vS[2][128 * 64];
  __shared__ __align__(16) u16 pS[4][16 * 64];

  const size_t headq = (size_t)(b * HEADS + h) * SEQ;
  const u16* kbase = kr + headq * DH;
  const u16* vbase = vT + (size_t)(b * HEADS + h) * DH * SEQ;

  auto stageKV = [&](int buf, int kt) {        // 8 issues/thread (K:4, V:4)
    #pragma unroll
    for (int c = 0; c < 4; ++c) {
      int chunk = (wave * 4 + c) * 64 + lane;          // 0..1023
      int row = chunk >> 4;
      int scolb = ((chunk & 15) << 4) ^ ((row & 7) << 4);
      gload_lds16(kbase + (size_t)(kt * 64 + row) * DH + (scolb >> 1),
                  kT[buf] + (wave * 4 + c) * 64 * 8);
    }
    #pragma unroll
    for (int c = 0; c < 4; ++c) {
      int chunk = (wave * 4 + c) * 64 + lane;
      int d = chunk >> 3;
      int sb = ((chunk & 7) << 4) ^ ((d & 7) << 4);
      gload_lds16(vbase + (size_t)d * SEQ + kt * 64 + (sb >> 1),
                  vS[buf] + (wave * 4 + c) * 64 * 8);
    }
  };

  const f32x4 z4 = {0.f, 0.f, 0.f, 0.f};

  #pragma unroll 1
  for (int pass = 0; pass < 2; ++pass) {
    const int qt = pass ? (31 - pairi) : pairi;
    const int nkv = qt + 1;

    const u16* qbase = qr + (headq + qt * 64 + wave * 16) * DH;
    bf16x8 qf[4];
    #pragma unroll
    for (int ks = 0; ks < 4; ++ks)
      qf[ks] = *(const bf16x8*)(qbase + r * DH + ks * 32 + g * 8);

    f32x4 o[8];
    #pragma unroll
    for (int i = 0; i < 8; ++i) o[i] = z4;
    float m = -3.0e38f, lsum = 0.f;        // per-lane scalars (q = r)

    stageKV(0, 0);
    __syncthreads();

    for (int kt = 0; kt < nkv; ++kt) {
      const int cur = kt & 1;
      if (kt + 1 < nkv) stageKV(cur ^ 1, kt + 1);

      // S^T: lane(r,g), reg rr: k = nt*16 + g*4 + rr, q = r
      f32x4 s[4];
      #pragma unroll
      for (int i = 0; i < 4; ++i) s[i] = z4;
      __builtin_amdgcn_s_setprio(1);
      #pragma unroll
      for (int ks = 0; ks < 4; ++ks) {
        #pragma unroll
        for (int nt = 0; nt < 4; ++nt) {
          int krow = nt * 16 + r;
          int koff = krow * 128 + (((ks * 64 + g * 16) ^ ((krow & 7) << 4)) >> 1);
          bf16x8 kf = *(const bf16x8*)&kT[cur][koff];
          s[nt] = mfma16(kf, qf[ks], s[nt]);   // SWAPPED operands
        }
      }
      __builtin_amdgcn_s_setprio(0);

      if (kt == qt) {                    // diagonal causal mask: k > q
        #pragma unroll
        for (int nt = 0; nt < 4; ++nt)
          #pragma unroll
          for (int rr = 0; rr < 4; ++rr) {
            int kloc = nt * 16 + g * 4 + rr;
            int qloc = wave * 16 + r;
            if (kloc > qloc) s[nt][rr] = -1e30f;
          }
      }

      float mx = s[0][0];
      #pragma unroll
      for (int nt = 0; nt < 4; ++nt)
        #pragma unroll
        for (int rr = 0; rr < 4; ++rr)
          mx = fmaxf(mx, s[nt][rr]);
      mx = fmaxf(mx, __shfl_xor(mx, 16));
      mx = fmaxf(mx, __shfl_xor(mx, 32));
      float mnew = fmaxf(m, mx);
      float alpha = exp2f(m - mnew);
      m = mnew;

      float rs = 0.f;
      float p[4][4];
      #pragma unroll
      for (int nt = 0; nt < 4; ++nt)
        #pragma unroll
        for (int rr = 0; rr < 4; ++rr) {
          p[nt][rr] = exp2f(s[nt][rr] - mnew);
          rs += p[nt][rr];
        }
      rs += __shfl_xor(rs, 16);
      rs += __shfl_xor(rs, 32);
      lsum = lsum * alpha + rs;
      #pragma unroll
      for (int dt = 0; dt < 8; ++dt)
        o[dt] *= alpha;

      // pack P -> LDS: 4x b64 per lane at [q=r][k = nt*16+g*4 .. +3]
      #pragma unroll
      for (int nt = 0; nt < 4; ++nt) {
        bf16x4 pk;
        pk[0] = (short)f2bf(p[nt][0]); pk[1] = (short)f2bf(p[nt][1]);
        pk[2] = (short)f2bf(p[nt][2]); pk[3] = (short)f2bf(p[nt][3]);
        int elem = r * 64 + ((nt * 16 + g * 4) ^ ((r & 7) << 3));
        *(bf16x4*)&pS[wave][elem] = pk;
      }

      // O^T += V(A) x P(B): lane(r,g) rr: d = dt*16+g*4+rr, q = r
      __builtin_amdgcn_s_setprio(1);
      #pragma unroll
      for (int ks = 0; ks < 2; ++ks) {
        int pfe = r * 64 + ((ks * 32 + g * 8) ^ ((r & 7) << 3));
        bf16x8 pf = *(const bf16x8*)&pS[wave][pfe];
        #pragma unroll
        for (int dt = 0; dt < 8; ++dt) {
          int vrow = dt * 16 + r;
          int voff = vrow * 64 + (((ks * 64 + g * 16) ^ ((vrow & 7) << 4)) >> 1);
          bf16x8 vf = *(const bf16x8*)&vS[cur][voff];
          o[dt] = mfma16(vf, pf, o[dt]);   // SWAPPED: V as A, P as B
        }
      }
      __builtin_amdgcn_s_setprio(0);

      __syncthreads();   // drains prefetch; guards buffer reuse
    }

    // epilogue: O^T -> LDS transpose (per-wave, reuses pS) -> coalesced store
    float inv = 1.0f / lsum;
    #pragma unroll
    for (int dh = 0; dh < 2; ++dh) {
      #pragma unroll
      for (int dt4 = 0; dt4 < 4; ++dt4) {
        int dt = dh * 4 + dt4;
        bf16x4 ovp;
        ovp[0] = (short)f2bf(o[dt][0] * inv);
        ovp[1] = (short)f2bf(o[dt][1] * inv);
        ovp[2] = (short)f2bf(o[dt][2] * inv);
        ovp[3] = (short)f2bf(o[dt][3] * inv);
        int elem = r * 64 + (((dt4 * 16 + g * 4)) ^ ((r & 7) << 3));
        *(bf16x4*)&pS[wave][elem] = ovp;
      }
      #pragma unroll
      for (int i = 0; i < 2; ++i) {
        int c = i * 64 + lane;
        int qq = c >> 3, dc = c & 7;
        int elem = qq * 64 + ((dc * 8) ^ ((qq & 7) << 3));
        uint4 val = *(const uint4*)&pS[wave][elem];
        *(uint4*)&attn[((size_t)b * SEQ + qt * 64 + wave * 16 + qq) * INNER +
                       h * DH + dh * 64 + dc * 8] = val;
      }
    }
    __syncthreads();
  }
}

// ---------------- host ----------------
extern "C" void kernel_launch(void* const* d_in, const int* in_sizes, int n_in,
                              void* d_out, int out_size, void* d_ws, size_t ws_size,
                              hipStream_t stream) {
  const float* x   = (const float*)d_in[0];
  const float* rot = (const float*)d_in[1];
  const float* g   = (const float*)d_in[2];
  const float* Wq  = (const float*)d_in[3];
  const float* Wkv = (const float*)d_in[4];
  const float* Wo  = (const float*)d_in[5];

  char* ws = (char*)d_ws;
  size_t off = 0;
  auto alloc = [&](size_t bytes) {
    char* p = ws + off;
    off += (bytes + 255) & ~(size_t)255;
    return p;
  };
  u16*   WqkvT = (u16*)alloc((size_t)6144 * 2048 * 2);  // q rows 0-2047, k 2048-4095, v 4096-6143
  u16*   WoT   = (u16*)alloc((size_t)2048 * 2048 * 2);
  u16*   cosT  = (u16*)alloc((size_t)2048 * 128 * 2);
  u16*   sinT  = (u16*)alloc((size_t)2048 * 128 * 2);
  u16*   xn    = (u16*)alloc((size_t)4096 * 2048 * 2);
  u16*   qkv   = (u16*)alloc((size_t)4096 * 6144 * 2);
  u16*   qr    = (u16*)alloc((size_t)4096 * 2048 * 2);
  // region reuse (dependency-checked against launch order below):
  u16* kr   = WqkvT;  // WqkvT (25.2MB >= 16.8MB) dead after QKV GEMM
  u16* vt   = xn;     // xn dead after QKV GEMM
  u16* attn = qkv;    // qkv dead after rope_fused (reads all of q,k,v)

  // rope-q scale = 1/sqrt(128) * log2(e)  (softmax runs in exp2 domain)
  const float qscale = 0.08838834764831845f * 1.4426950408889634f;

  transpose_cast<<<dim3(1024), 256, 0, stream>>>(Wq,  WqkvT,               2048, 2048);
  transpose_cast<<<dim3(2048), 256, 0, stream>>>(Wkv, WqkvT + 2048 * 2048, 2048, 4096);
  transpose_cast<<<dim3(1024), 256, 0, stream>>>(Wo,  WoT,                 2048, 2048);
  build_tables<<<dim3(2048 * 128 / 256), 256, 0, stream>>>(rot, cosT, sinT);
  rmsnorm_k<<<dim3(4096), 256, 0, stream>>>(x, g, xn);
  gemm_qkv<<<dim3(768), 512, 0, stream>>>(xn, WqkvT, qkv, 4096, 6144, 2048);
  rope_fused<<<dim3(2048), 256, 0, stream>>>(qkv, cosT, sinT, qr, kr, vt, qscale);
  flash<<<dim3(512), 256, 0, stream>>>(qr, kr, vt, attn);
  gemm128<1><<<dim3(512), 256, 0, stream>>>(attn, WoT, (float*)d_out, 4096, 2048, 2048);
}